// Round 10
// baseline (339.206 us; speedup 1.0000x reference)
//
#include <hip/hip_runtime.h>
#include <hip/hip_bf16.h>

// B=16, C=2048, T=128, ID=32, NC=16, CD=32, GD=32, OUT=96, GIN=192
// ws (floats): vt(bf16) @0 (3,145,728) | geb16(bf16) @3145728 (524,288) |
// aggb(bf16) @3670016 (3,145,728) | wraw @6815744 (589,824) |
// m2 @7405568 (294,912) | sumv @7700480 (3,072) |
// wpart @7703552 (4,718,592) | cwhi/cwlo(bf16) @12422144 (393,216 f-eq)
//   => 51.3 MB full (30.8 min fallback).
//
// ADJACENCY SEMANTICS: weight(m) = 0 if m==o; exp(s) if s>0; 1 if s<=0.
// Decomposition: d = weight-1 (d=-1 diag, exp(s)-1 if s>0, else 0).
// agg_unnorm = sumV + MFMA(d,V);  l = 2048 + sum(d).
//
// Round-22: k3 -> bf16 MFMA w/ cw hi/lo split: 291.4 -> 274.0 (matched).
// Round-23: k2 LDS 48KB single-buffer sVt: FAILED (65.8->69.4; occupancy
//           是 GRID-capped at 2 blocks/CU — LDS was never binding).
// Round-24 (this round): k2 -> 512 threads, producer/consumer wave split.
//   Waves 0-3 (t<256): compute only (MFMA1 w/ A-regs, exp->dw, MFMA2).
//   Waves 4-7: staging only (issue next-tile loads at iter top; write
//   dbuf sGe/sVt after B1). Same 2-barrier skeleton as verified round-8.
//   16 waves/CU (was 8). LDS 75,776B (2 blocks/CU); launch_bounds(512,4)
//   caps VGPR at 128 (current 116).
// Prediction: k2 occ 19->30-38%, MfmaUtil 17->24-30%, dur -> 45-55us;
//   total ~252-262. Failure mode: VGPR>128 -> 1 block/CU -> neutral.

typedef __attribute__((ext_vector_type(8))) short short8;
typedef __attribute__((ext_vector_type(16))) float f32x16;

__device__ __forceinline__ unsigned short f2bf(float f) {
    __hip_bfloat16 h = __float2bfloat16(f);
    return *reinterpret_cast<unsigned short*>(&h);
}
__device__ __forceinline__ float bf2f(unsigned short u) {
    __hip_bfloat16 h = *reinterpret_cast<__hip_bfloat16*>(&u);
    return __bfloat162float(h);
}

// ---------------------------------------------------------------------------
// k0: transpose x (fp32 [b][m][128]) -> VT bf16 [b][ch][m] for ch 0..127.
// ---------------------------------------------------------------------------
__global__ __launch_bounds__(256) void k0_transpose_x(
    const float* __restrict__ x, unsigned short* __restrict__ vt)
{
    __shared__ float sT[64 * 133];
    const int t = threadIdx.x;
    const int m0 = blockIdx.x * 64;
    const int b = blockIdx.y;
    const float* xb = x + (size_t)b * 2048 * 128;
    #pragma unroll
    for (int kk = 0; kk < 8; ++kk) {
        int i = t + kk * 256;
        int mm = i >> 5, q4 = i & 31;
        float4 v = ((const float4*)(xb + (size_t)(m0 + mm) * 128))[q4];
        float* d = sT + mm * 133 + q4 * 4;
        d[0] = v.x; d[1] = v.y; d[2] = v.z; d[3] = v.w;
    }
    __syncthreads();
    const int mp = t & 31;
    const int ch0 = t >> 5;
    #pragma unroll
    for (int pass = 0; pass < 16; ++pass) {
        int ch = ch0 + pass * 8;
        unsigned int u0 = f2bf(sT[(2 * mp) * 133 + ch]);
        unsigned int u1 = f2bf(sT[(2 * mp + 1) * 133 + ch]);
        *((unsigned int*)(vt + (size_t)(b * 192 + ch) * 2048 + m0) + mp) =
            u0 | (u1 << 16);
    }
}

// ---------------------------------------------------------------------------
// k1_tiled: 32 rows per block (grid 1024, 256 thr). Phase B reads x directly.
// ---------------------------------------------------------------------------
__global__ __launch_bounds__(256) void k1_tiled(
    const float* __restrict__ x, const float* __restrict__ id_emb,
    const float* __restrict__ w1, const float* __restrict__ b1,
    const float* __restrict__ w2, const float* __restrict__ b2,
    const float* __restrict__ ce, const float* __restrict__ wic,
    const float* __restrict__ bic, const float* __restrict__ wg,
    const float* __restrict__ bg, unsigned short* __restrict__ vt,
    unsigned short* __restrict__ geb16)
{
    __shared__ float sh[32 * 68];
    __shared__ float sid[32 * 36];
    __shared__ float sic[32 * 36];
    __shared__ float scl[32 * 36];
    __shared__ float sp[32 * 20];

    const int t = threadIdx.x;
    const int r0 = blockIdx.x * 32;     // 32-row blocks never cross a batch
    const int b = r0 >> 11;
    const int c0 = r0 & 2047;

    // Phase B: h = relu(xs@w1 + b1). row=t>>3, 8 cols per thread.
    {
        const int row = t >> 3, j0 = (t & 7) * 8;
        const float* xrow = x + (size_t)(r0 + row) * 128;
        float acc[8];
        #pragma unroll
        for (int j = 0; j < 8; ++j) acc[j] = b1[j0 + j];
        float4 pa[4], pb[4];
        float4 pxv;
        #pragma unroll
        for (int u = 0; u < 4; ++u) {
            const float4* wr = (const float4*)(w1 + u * 64 + j0);
            pa[u] = wr[0]; pb[u] = wr[1];
        }
        pxv = *(const float4*)(xrow);
        for (int k0 = 0; k0 < 128; k0 += 4) {
            float4 ca[4], cb[4];
            float4 cxv = pxv;
            #pragma unroll
            for (int u = 0; u < 4; ++u) { ca[u] = pa[u]; cb[u] = pb[u]; }
            const int kn = k0 + 4;
            if (kn < 128) {
                #pragma unroll
                for (int u = 0; u < 4; ++u) {
                    const float4* wr = (const float4*)(w1 + (kn + u) * 64 + j0);
                    pa[u] = wr[0]; pb[u] = wr[1];
                }
                pxv = *(const float4*)(xrow + kn);
            }
            float cx[4] = {cxv.x, cxv.y, cxv.z, cxv.w};
            #pragma unroll
            for (int u = 0; u < 4; ++u) {
                acc[0] = fmaf(cx[u], ca[u].x, acc[0]);
                acc[1] = fmaf(cx[u], ca[u].y, acc[1]);
                acc[2] = fmaf(cx[u], ca[u].z, acc[2]);
                acc[3] = fmaf(cx[u], ca[u].w, acc[3]);
                acc[4] = fmaf(cx[u], cb[u].x, acc[4]);
                acc[5] = fmaf(cx[u], cb[u].y, acc[5]);
                acc[6] = fmaf(cx[u], cb[u].z, acc[6]);
                acc[7] = fmaf(cx[u], cb[u].w, acc[7]);
            }
        }
        float* hr = sh + row * 68 + j0;
        #pragma unroll
        for (int j = 0; j < 8; ++j) hr[j] = fmaxf(acc[j], 0.f);
    }
    __syncthreads();

    // Phase C: ide = id_emb + h@w2 + b2. row=t>>3, 4 cols per thread.
    {
        const int row = t >> 3, j0 = (t & 7) * 4;
        const int c = c0 + row;
        const float* hrow = sh + row * 68;
        float acc[4];
        #pragma unroll
        for (int j = 0; j < 4; ++j) acc[j] = b2[j0 + j];
        float4 pw[4];
        float  ph[4];
        #pragma unroll
        for (int u = 0; u < 4; ++u) {
            pw[u] = *(const float4*)(w2 + u * 32 + j0);
            ph[u] = hrow[u];
        }
        for (int k0 = 0; k0 < 64; k0 += 4) {
            float4 cw4[4];
            float  ch4[4];
            #pragma unroll
            for (int u = 0; u < 4; ++u) { cw4[u] = pw[u]; ch4[u] = ph[u]; }
            const int kn = k0 + 4;
            if (kn < 64) {
                #pragma unroll
                for (int u = 0; u < 4; ++u) {
                    pw[u] = *(const float4*)(w2 + (kn + u) * 32 + j0);
                    ph[u] = hrow[kn + u];
                }
            }
            #pragma unroll
            for (int u = 0; u < 4; ++u) {
                acc[0] = fmaf(ch4[u], cw4[u].x, acc[0]);
                acc[1] = fmaf(ch4[u], cw4[u].y, acc[1]);
                acc[2] = fmaf(ch4[u], cw4[u].z, acc[2]);
                acc[3] = fmaf(ch4[u], cw4[u].w, acc[3]);
            }
        }
        #pragma unroll
        for (int j = 0; j < 4; ++j) {
            float ide = id_emb[c * 32 + j0 + j] + acc[j];
            sid[row * 36 + j0 + j] = ide;
            vt[(size_t)(b * 192 + 128 + j0 + j) * 2048 + c] = f2bf(ide);
        }
    }
    __syncthreads();

    // Phase D: ic = id_e@wic + bic. Same mapping, pipelined.
    {
        const int row = t >> 3, j0 = (t & 7) * 4;
        const float* irow = sid + row * 36;
        float acc[4];
        #pragma unroll
        for (int j = 0; j < 4; ++j) acc[j] = bic[j0 + j];
        float4 pw[4];
        float  pi[4];
        #pragma unroll
        for (int u = 0; u < 4; ++u) {
            pw[u] = *(const float4*)(wic + u * 32 + j0);
            pi[u] = irow[u];
        }
        for (int k0 = 0; k0 < 32; k0 += 4) {
            float4 cw4[4];
            float  ci4[4];
            #pragma unroll
            for (int u = 0; u < 4; ++u) { cw4[u] = pw[u]; ci4[u] = pi[u]; }
            const int kn = k0 + 4;
            if (kn < 32) {
                #pragma unroll
                for (int u = 0; u < 4; ++u) {
                    pw[u] = *(const float4*)(wic + (kn + u) * 32 + j0);
                    pi[u] = irow[kn + u];
                }
            }
            #pragma unroll
            for (int u = 0; u < 4; ++u) {
                acc[0] = fmaf(ci4[u], cw4[u].x, acc[0]);
                acc[1] = fmaf(ci4[u], cw4[u].y, acc[1]);
                acc[2] = fmaf(ci4[u], cw4[u].z, acc[2]);
                acc[3] = fmaf(ci4[u], cw4[u].w, acc[3]);
            }
        }
        #pragma unroll
        for (int j = 0; j < 4; ++j) sic[row * 36 + j0 + j] = acc[j];
    }
    __syncthreads();

    // Phase E: logits. n=t&15, rows t>>4 and (t>>4)+16. Batched loads.
    {
        const int n = t & 15, rowp = t >> 4;
        const float* cer = ce + n * 32;
        float a0 = 0.f, a1 = 0.f;
        #pragma unroll
        for (int k0 = 0; k0 < 32; k0 += 8) {
            float cv[8], s0[8], s1[8];
            #pragma unroll
            for (int u = 0; u < 8; ++u) {
                cv[u] = cer[k0 + u];
                s0[u] = sic[rowp * 36 + k0 + u];
                s1[u] = sic[(rowp + 16) * 36 + k0 + u];
            }
            #pragma unroll
            for (int u = 0; u < 8; ++u) {
                a0 = fmaf(s0[u], cv[u], a0);
                a1 = fmaf(s1[u], cv[u], a1);
            }
        }
        sp[rowp * 20 + n] = a0;
        sp[(rowp + 16) * 20 + n] = a1;
    }
    __syncthreads();

    // Phase F: softmax over 16 clusters, one thread per row (serial).
    if (t < 32) {
        float* pr = sp + t * 20;
        float mx = pr[0];
        for (int n = 1; n < 16; ++n) mx = fmaxf(mx, pr[n]);
        float ss = 0.f;
        for (int n = 0; n < 16; ++n) { float e = __expf(pr[n] - mx); pr[n] = e; ss += e; }
        float inv = 1.f / ss;
        for (int n = 0; n < 16; ++n) pr[n] *= inv;
    }
    __syncthreads();

    // Phase G: cl = p@ce. row=t>>3, 4 cols per thread, pipelined.
    {
        const int row = t >> 3, j0 = (t & 7) * 4;
        const int c = c0 + row;
        const float* prow = sp + row * 20;
        float acc[4] = {0.f, 0.f, 0.f, 0.f};
        float4 pc[4];
        float  pp[4];
        #pragma unroll
        for (int u = 0; u < 4; ++u) {
            pc[u] = *(const float4*)(ce + u * 32 + j0);
            pp[u] = prow[u];
        }
        for (int n0 = 0; n0 < 16; n0 += 4) {
            float4 cc4[4];
            float  cp4[4];
            #pragma unroll
            for (int u = 0; u < 4; ++u) { cc4[u] = pc[u]; cp4[u] = pp[u]; }
            const int nn = n0 + 4;
            if (nn < 16) {
                #pragma unroll
                for (int u = 0; u < 4; ++u) {
                    pc[u] = *(const float4*)(ce + (nn + u) * 32 + j0);
                    pp[u] = prow[nn + u];
                }
            }
            #pragma unroll
            for (int u = 0; u < 4; ++u) {
                acc[0] = fmaf(cp4[u], cc4[u].x, acc[0]);
                acc[1] = fmaf(cp4[u], cc4[u].y, acc[1]);
                acc[2] = fmaf(cp4[u], cc4[u].z, acc[2]);
                acc[3] = fmaf(cp4[u], cc4[u].w, acc[3]);
            }
        }
        #pragma unroll
        for (int j = 0; j < 4; ++j) {
            scl[row * 36 + j0 + j] = acc[j];
            vt[(size_t)(b * 192 + 160 + j0 + j) * 2048 + c] = f2bf(acc[j]);
        }
    }
    __syncthreads();

    // Phase H: ge = [id|cl]@wg + bg -> bf16. Two pipelined 32-loops.
    {
        const int row = t >> 3, j0 = (t & 7) * 4;
        const int r = r0 + row;
        const float* irow = sid + row * 36;
        const float* crow = scl + row * 36;
        float acc[4];
        #pragma unroll
        for (int j = 0; j < 4; ++j) acc[j] = bg[j0 + j];
        // id part
        {
            float4 pw[4];
            float  pi[4];
            #pragma unroll
            for (int u = 0; u < 4; ++u) {
                pw[u] = *(const float4*)(wg + u * 32 + j0);
                pi[u] = irow[u];
            }
            for (int k0 = 0; k0 < 32; k0 += 4) {
                float4 cw4[4];
                float  ci4[4];
                #pragma unroll
                for (int u = 0; u < 4; ++u) { cw4[u] = pw[u]; ci4[u] = pi[u]; }
                const int kn = k0 + 4;
                if (kn < 32) {
                    #pragma unroll
                    for (int u = 0; u < 4; ++u) {
                        pw[u] = *(const float4*)(wg + (kn + u) * 32 + j0);
                        pi[u] = irow[kn + u];
                    }
                }
                #pragma unroll
                for (int u = 0; u < 4; ++u) {
                    acc[0] = fmaf(ci4[u], cw4[u].x, acc[0]);
                    acc[1] = fmaf(ci4[u], cw4[u].y, acc[1]);
                    acc[2] = fmaf(ci4[u], cw4[u].z, acc[2]);
                    acc[3] = fmaf(ci4[u], cw4[u].w, acc[3]);
                }
            }
        }
        // cl part
        {
            float4 pw[4];
            float  pcv[4];
            #pragma unroll
            for (int u = 0; u < 4; ++u) {
                pw[u] = *(const float4*)(wg + (32 + u) * 32 + j0);
                pcv[u] = crow[u];
            }
            for (int k0 = 0; k0 < 32; k0 += 4) {
                float4 cw4[4];
                float  cc4[4];
                #pragma unroll
                for (int u = 0; u < 4; ++u) { cw4[u] = pw[u]; cc4[u] = pcv[u]; }
                const int kn = k0 + 4;
                if (kn < 32) {
                    #pragma unroll
                    for (int u = 0; u < 4; ++u) {
                        pw[u] = *(const float4*)(wg + (32 + kn + u) * 32 + j0);
                        pcv[u] = crow[kn + u];
                    }
                }
                #pragma unroll
                for (int u = 0; u < 4; ++u) {
                    acc[0] = fmaf(cc4[u], cw4[u].x, acc[0]);
                    acc[1] = fmaf(cc4[u], cw4[u].y, acc[1]);
                    acc[2] = fmaf(cc4[u], cw4[u].z, acc[2]);
                    acc[3] = fmaf(cc4[u], cw4[u].w, acc[3]);
                }
            }
        }
        #pragma unroll
        for (int j = 0; j < 4; ++j)
            geb16[(size_t)r * 32 + j0 + j] = f2bf(acc[j]);
    }
}

// ---------------------------------------------------------------------------
// k1b: sumV[b][ch] = sum_m VT[b][ch][m] (fp32 accumulate of bf16).
// ---------------------------------------------------------------------------
__global__ __launch_bounds__(256) void k1b_sumv(
    const unsigned short* __restrict__ vt, float* __restrict__ sumv)
{
    __shared__ float red[256];
    const int ch = blockIdx.x, b = blockIdx.y, t = threadIdx.x;
    const unsigned short* row = vt + (size_t)(b * 192 + ch) * 2048;
    float a = 0.f;
    #pragma unroll
    for (int j = 0; j < 8; ++j) a += bf2f(row[t * 8 + j]);
    red[t] = a; __syncthreads();
    for (int off = 128; off > 0; off >>= 1) {
        if (t < off) red[t] += red[t + off];
        __syncthreads();
    }
    if (t == 0) sumv[b * 192 + ch] = red[0];
}

// ---------------------------------------------------------------------------
// k2: all-MFMA core. Round-24: 512 threads, producer/consumer wave split.
// Waves 0-3 compute (A-regs, MFMA1, exp->dw, MFMA2); waves 4-7 stage
// (global loads at iter top, dbuf LDS writes after B1). 2 barriers/iter,
// same skeleton as verified round-8. LDS 75,776 B -> 2 blocks/CU,
// 16 waves/CU. XCD remap + diag hoist kept.
// ---------------------------------------------------------------------------
__global__ __launch_bounds__(512, 4) void k2_fused(
    const unsigned short* __restrict__ geb16,
    const unsigned short* __restrict__ vt,
    const float* __restrict__ sumv,
    unsigned short* __restrict__ aggb)
{
    __shared__ unsigned short sGe[2][64 * 40];   // 10240 B
    __shared__ unsigned short sVtA[2][192 * 72]; // 55296 B
    __shared__ unsigned short dw[64 * 72];       //  9216 B
    __shared__ float s_sum[192];                 //   768 B
    __shared__ float sinv[64];                   //   256 B
    float* lpbuf = (float*)sVtA;   // [64][68] fp32, post-loop only

    const int t = threadIdx.x;
    const int tc = t & 255;
    const int role = t >> 8;       // 0 = compute waves, 1 = producer waves

    // XCD-bijective remap: 512 blocks = 8 XCDs x 64.
    const int lin = blockIdx.x + gridDim.x * blockIdx.y;   // 0..511
    const int nb = (lin & 7) * 64 + (lin >> 3);
    const int o0 = (nb & 31) * 64;
    const int b = nb >> 5;
    const unsigned short* geb = geb16 + (size_t)b * 2048 * 32;
    const unsigned short* vtb = vt + (size_t)b * 192 * 2048;

    const int lane = tc & 63;
    const int mg = tc >> 6;
    const int col = lane & 31;
    const int grp = lane >> 5;
    const int os = (mg & 1) * 32;
    const int ms = (mg >> 1) * 32;
    const int orow0 = (mg & 1) * 32;
    const int dbase = (mg >> 1) * 96;

    const int ge_row = tc >> 2, ge_c8 = tc & 3;

    if (t < 192) s_sum[t] = sumv[b * 192 + t];

    short8 Areg0, Areg1;
    short8 rGe, rVt0, rVt1, rVt2, rVt3, rVt4, rVt5;

    if (role == 0) {
        // A-fragments for MFMA1 are iteration-invariant.
        Areg0 = *(const short8*)(geb + (size_t)(o0 + os + col) * 32 + 0 * 16 + grp * 8);
        Areg1 = *(const short8*)(geb + (size_t)(o0 + os + col) * 32 + 1 * 16 + grp * 8);
    } else {
        // Prologue: stage tile 0 into buffer 0.
        rGe = *(const short8*)(geb + (size_t)ge_row * 32 + ge_c8 * 8);
        int i0;
        i0 = tc + 0 * 256; rVt0 = *(const short8*)(vtb + (size_t)(i0 >> 3) * 2048 + 0 + (i0 & 7) * 8);
        i0 = tc + 1 * 256; rVt1 = *(const short8*)(vtb + (size_t)(i0 >> 3) * 2048 + 0 + (i0 & 7) * 8);
        i0 = tc + 2 * 256; rVt2 = *(const short8*)(vtb + (size_t)(i0 >> 3) * 2048 + 0 + (i0 & 7) * 8);
        i0 = tc + 3 * 256; rVt3 = *(const short8*)(vtb + (size_t)(i0 >> 3) * 2048 + 0 + (i0 & 7) * 8);
        i0 = tc + 4 * 256; rVt4 = *(const short8*)(vtb + (size_t)(i0 >> 3) * 2048 + 0 + (i0 & 7) * 8);
        i0 = tc + 5 * 256; rVt5 = *(const short8*)(vtb + (size_t)(i0 >> 3) * 2048 + 0 + (i0 & 7) * 8);
        *(short8*)(sGe[0] + ge_row * 40 + ge_c8 * 8) = rGe;
        i0 = tc + 0 * 256; *(short8*)(sVtA[0] + (i0 >> 3) * 72 + (i0 & 7) * 8) = rVt0;
        i0 = tc + 1 * 256; *(short8*)(sVtA[0] + (i0 >> 3) * 72 + (i0 & 7) * 8) = rVt1;
        i0 = tc + 2 * 256; *(short8*)(sVtA[0] + (i0 >> 3) * 72 + (i0 & 7) * 8) = rVt2;
        i0 = tc + 3 * 256; *(short8*)(sVtA[0] + (i0 >> 3) * 72 + (i0 & 7) * 8) = rVt3;
        i0 = tc + 4 * 256; *(short8*)(sVtA[0] + (i0 >> 3) * 72 + (i0 & 7) * 8) = rVt4;
        i0 = tc + 5 * 256; *(short8*)(sVtA[0] + (i0 >> 3) * 72 + (i0 & 7) * 8) = rVt5;
    }
    __syncthreads();

    f32x16 acc0, acc1, acc2;
    #pragma unroll
    for (int i = 0; i < 16; ++i) { acc0[i] = 0.f; acc1[i] = 0.f; acc2[i] = 0.f; }
    float lpA[16];
    #pragma unroll
    for (int i = 0; i < 16; ++i) lpA[i] = 0.f;

    int cur = 0;
    for (int m0 = 0; m0 < 2048; m0 += 64) {
        const bool have_next = (m0 + 64 < 2048);

        if (role == 1) {
            // Producers: issue next tile's global loads (in flight across B1).
            if (have_next) {
                const int mn = m0 + 64;
                rGe = *(const short8*)(geb + (size_t)(mn + ge_row) * 32 + ge_c8 * 8);
                int i0;
                i0 = tc + 0 * 256; rVt0 = *(const short8*)(vtb + (size_t)(i0 >> 3) * 2048 + mn + (i0 & 7) * 8);
                i0 = tc + 1 * 256; rVt1 = *(const short8*)(vtb + (size_t)(i0 >> 3) * 2048 + mn + (i0 & 7) * 8);
                i0 = tc + 2 * 256; rVt2 = *(const short8*)(vtb + (size_t)(i0 >> 3) * 2048 + mn + (i0 & 7) * 8);
                i0 = tc + 3 * 256; rVt3 = *(const short8*)(vtb + (size_t)(i0 >> 3) * 2048 + mn + (i0 & 7) * 8);
                i0 = tc + 4 * 256; rVt4 = *(const short8*)(vtb + (size_t)(i0 >> 3) * 2048 + mn + (i0 & 7) * 8);
                i0 = tc + 5 * 256; rVt5 = *(const short8*)(vtb + (size_t)(i0 >> 3) * 2048 + mn + (i0 & 7) * 8);
            }
        } else {
            // MFMA1: adjacency scores (A from regs, B from sGe[cur]).
            f32x16 sacc;
            #pragma unroll
            for (int i = 0; i < 16; ++i) sacc[i] = 0.f;
            {
                short8 Bf0 = *(const short8*)(sGe[cur] + (ms + col) * 40 + 0 * 16 + grp * 8);
                short8 Bf1 = *(const short8*)(sGe[cur] + (ms + col) * 40 + 1 * 16 + grp * 8);
                sacc = __builtin_amdgcn_mfma_f32_32x32x16_bf16(Areg0, Bf0, sacc, 0, 0, 0);
                sacc = __builtin_amdgcn_mfma_f32_32x32x16_bf16(Areg1, Bf1, sacc, 0, 0, 0);
            }
            const int m_local = ms + col;
            if (m0 != o0) {              // no diagonal in this tile
                #pragma unroll
                for (int r = 0; r < 16; ++r) {
                    int o_local = os + (r & 3) + 8 * (r >> 2) + 4 * grp;
                    float s = sacc[r];
                    float d = (s > 0.f) ? (__expf(s) - 1.f) : 0.f;
                    lpA[r] += d;
                    dw[o_local * 72 + m_local] = f2bf(d);
                }
            } else {
                const int gm = m0 + m_local;
                #pragma unroll
                for (int r = 0; r < 16; ++r) {
                    int o_local = os + (r & 3) + 8 * (r >> 2) + 4 * grp;
                    float s = sacc[r];
                    float d = (gm == o0 + o_local) ? -1.f
                            : ((s > 0.f) ? (__expf(s) - 1.f) : 0.f);
                    lpA[r] += d;
                    dw[o_local * 72 + m_local] = f2bf(d);
                }
            }
        }

        __syncthreads();   // B1: dw ready

        if (role == 0) {
            // MFMA2: agg += d @ V for this tile.
            #pragma unroll
            for (int ks = 0; ks < 4; ++ks) {
                short8 A   = *(const short8*)(dw + (orow0 + col) * 72 + ks * 16 + grp * 8);
                short8 B0v = *(const short8*)(sVtA[cur] + (dbase + col) * 72 + ks * 16 + grp * 8);
                short8 B1v = *(const short8*)(sVtA[cur] + (dbase + 32 + col) * 72 + ks * 16 + grp * 8);
                short8 B2v = *(const short8*)(sVtA[cur] + (dbase + 64 + col) * 72 + ks * 16 + grp * 8);
                acc0 = __builtin_amdgcn_mfma_f32_32x32x16_bf16(A, B0v, acc0, 0, 0, 0);
                acc1 = __builtin_amdgcn_mfma_f32_32x32x16_bf16(A, B1v, acc1, 0, 0, 0);
                acc2 = __builtin_amdgcn_mfma_f32_32x32x16_bf16(A, B2v, acc2, 0, 0, 0);
            }
        } else if (have_next) {
            // Producers: write prefetched tile into the other buffers.
            const int nbuf = cur ^ 1;
            *(short8*)(sGe[nbuf] + ge_row * 40 + ge_c8 * 8) = rGe;
            int i0;
            i0 = tc + 0 * 256; *(short8*)(sVtA[nbuf] + (i0 >> 3) * 72 + (i0 & 7) * 8) = rVt0;
            i0 = tc + 1 * 256; *(short8*)(sVtA[nbuf] + (i0 >> 3) * 72 + (i0 & 7) * 8) = rVt1;
            i0 = tc + 2 * 256; *(short8*)(sVtA[nbuf] + (i0 >> 3) * 72 + (i0 & 7) * 8) = rVt2;
            i0 = tc + 3 * 256; *(short8*)(sVtA[nbuf] + (i0 >> 3) * 72 + (i0 & 7) * 8) = rVt3;
            i0 = tc + 4 * 256; *(short8*)(sVtA[nbuf] + (i0 >> 3) * 72 + (i0 & 7) * 8) = rVt4;
            i0 = tc + 5 * 256; *(short8*)(sVtA[nbuf] + (i0 >> 3) * 72 + (i0 & 7) * 8) = rVt5;
        }

        __syncthreads();   // B2: producer writes visible; dw/sVt reads done
        cur ^= 1;
    }

    if (role == 0) {
        const int widx = mg >> 1;
        #pragma unroll
        for (int r = 0; r < 16; ++r) {
            int ol = os + (r & 3) + 8 * (r >> 2) + 4 * grp;
            lpbuf[(widx * 32 + col) * 68 + ol] = lpA[r];
        }
    }
    __syncthreads();
    if (t < 64) {
        float l = 2048.f;
        for (int i = 0; i < 64; ++i) l += lpbuf[i * 68 + t];
        sinv[t] = 1.f / l;
    }
    __syncthreads();

    if (role == 0) {
        f32x16 av[3] = {acc0, acc1, acc2};
        unsigned short* ab = aggb + (size_t)b * 2048 * 192;
        #pragma unroll
        for (int n = 0; n < 3; ++n) {
            int chn = dbase + n * 32 + col;
            float sv = s_sum[chn];
            #pragma unroll
            for (int r = 0; r < 16; ++r) {
                int ol = orow0 + (r & 3) + 8 * (r >> 2) + 4 * grp;
                ab[(size_t)(o0 + ol) * 192 + chn] =
                    f2bf((sv + av[n][r]) * sinv[ol]);
            }
        }
    }
}

// ---------------------------------------------------------------------------
// k3a_split: cw (fp32 [2048][192]) -> cwhi + cwlo (bf16 each).
// ---------------------------------------------------------------------------
__global__ __launch_bounds__(256) void k3a_split(
    const float* __restrict__ cw, unsigned short* __restrict__ cwhi,
    unsigned short* __restrict__ cwlo)
{
    const int idx = blockIdx.x * 256 + threadIdx.x;   // grid 1536 -> 393216
    float v = cw[idx];
    unsigned short h = f2bf(v);
    cwhi[idx] = h;
    cwlo[idx] = f2bf(v - bf2f(h));
}

// ---------------------------------------------------------------------------
// k3_mfma_sk: wpart[slot][d][l] = sum_{o in ks-range} agg[o][d]*cw[o][l]
// via bf16 MFMA with cw hi/lo split. No LDS, no barriers.
// ---------------------------------------------------------------------------
__global__ __launch_bounds__(256) void k3_mfma_sk(
    const unsigned short* __restrict__ aggb,
    const unsigned short* __restrict__ cwhi,
    const unsigned short* __restrict__ cwlo,
    float* __restrict__ wpart)
{
    const int t = threadIdx.x;
    const int slot = blockIdx.z;
    const int b = slot >> 3;
    const int ks = slot & 7;
    const int d0 = blockIdx.x * 64;
    const int l0 = blockIdx.y * 64;
    const unsigned short* ab = aggb + (size_t)b * 2048 * 192;

    const int lane = t & 63;
    const int w = t >> 6;
    const int col = lane & 31;
    const int grp = lane >> 5;
    const int drow = d0 + (w & 1) * 32 + col;    // A row for this lane
    const int lrow = l0 + (w >> 1) * 32 + col;   // B row for this lane

    f32x16 acc;
    #pragma unroll
    for (int i = 0; i < 16; ++i) acc[i] = 0.f;

    const int obase = ks * 256;
    #pragma unroll 4
    for (int ostep = 0; ostep < 16; ++ostep) {
        const int ob = obase + ostep * 16 + grp * 8;
        short8 A, Bh, Bl;
        #pragma unroll
        for (int i = 0; i < 8; ++i) {
            const size_t ro = (size_t)(ob + i) * 192;
            A[i]  = (short)ab[ro + drow];
            Bh[i] = (short)cwhi[ro + lrow];
            Bl[i] = (short)cwlo[ro + lrow];
        }
        acc = __builtin_amdgcn_mfma_f32_32x32x16_bf16(A, Bh, acc, 0, 0, 0);
        acc = __builtin_amdgcn_mfma_f32_32x32x16_bf16(A, Bl, acc, 0, 0, 0);
    }

    float* wp = wpart + (size_t)slot * 36864;
    const int lcol = l0 + (w >> 1) * 32 + col;
    #pragma unroll
    for (int r = 0; r < 16; ++r) {
        int dl = d0 + (w & 1) * 32 + (r & 3) + 8 * (r >> 2) + 4 * grp;
        wp[(size_t)dl * 192 + lcol] = acc[r];
    }
}

// ---------------------------------------------------------------------------
// k3_ctx_sk: split-K partial of w-sum (fp32 fallback). blockIdx.z = b*8+ks.
// ---------------------------------------------------------------------------
__global__ __launch_bounds__(256) void k3_ctx_sk(
    const unsigned short* __restrict__ aggb, const float* __restrict__ cw,
    float* __restrict__ wpart)
{
    __shared__ float sA[64 * 68];
    __shared__ float sW[64 * 68];
    const int t = threadIdx.x;
    const int slot = blockIdx.z;
    const int b = slot >> 3;
    const int ks = slot & 7;
    const int d0 = blockIdx.x * 64;
    const int l0 = blockIdx.y * 64;
    const unsigned short* ab = aggb + (size_t)b * 2048 * 192;
    const int ti = t >> 4, tj = t & 15;
    float acc[4][4] = {{0.f}};

    for (int o0 = ks * 256; o0 < ks * 256 + 256; o0 += 64) {
        for (int i = t; i < 4096; i += 256) {
            int oo = i >> 6, dd = i & 63;
            sA[oo * 68 + dd] = bf2f(ab[(size_t)(o0 + oo) * 192 + d0 + dd]);
            sW[oo * 68 + dd] = cw[(size_t)(o0 + oo) * 192 + l0 + dd];
        }
        __syncthreads();
        for (int o = 0; o < 64; ++o) {
            const float* ap = sA + o * 68 + ti * 4;
            const float* wp = sW + o * 68 + tj * 4;
            float a0 = ap[0], a1 = ap[1], a2 = ap[2], a3 = ap[3];
            float w0 = wp[0], w1v = wp[1], w2v = wp[2], w3 = wp[3];
            acc[0][0] = fmaf(a0, w0, acc[0][0]); acc[0][1] = fmaf(a0, w1v, acc[0][1]);
            acc[0][2] = fmaf(a0, w2v, acc[0][2]); acc[0][3] = fmaf(a0, w3, acc[0][3]);
            acc[1][0] = fmaf(a1, w0, acc[1][0]); acc[1][1] = fmaf(a1, w1v, acc[1][1]);
            acc[1][2] = fmaf(a1, w2v, acc[1][2]); acc[1][3] = fmaf(a1, w3, acc[1][3]);
            acc[2][0] = fmaf(a2, w0, acc[2][0]); acc[2][1] = fmaf(a2, w1v, acc[2][1]);
            acc[2][2] = fmaf(a2, w2v, acc[2][2]); acc[2][3] = fmaf(a2, w3, acc[2][3]);
            acc[3][0] = fmaf(a3, w0, acc[3][0]); acc[3][1] = fmaf(a3, w1v, acc[3][1]);
            acc[3][2] = fmaf(a3, w2v, acc[3][2]); acc[3][3] = fmaf(a3, w3, acc[3][3]);
        }
        __syncthreads();
    }
    float* wp = wpart + (size_t)slot * 36864;
    #pragma unroll
    for (int i = 0; i < 4; ++i)
        #pragma unroll
        for (int j = 0; j < 4; ++j)
            wp[(d0 + ti * 4 + i) * 192 + l0 + tj * 4 + j] = acc[i][j];
}

// ---------------------------------------------------------------------------
__global__ __launch_bounds__(256) void k3r_reduce(
    const float* __restrict__ wpart, float* __restrict__ wraw)
{
    const int idx = blockIdx.x * 256 + threadIdx.x;
    const int b = blockIdx.y;
    const float* base = wpart + (size_t)b * 8 * 36864 + idx;
    float a = 0.f;
    #pragma unroll
    for (int ks = 0; ks < 8; ++ks) a += base[(size_t)ks * 36864];
    wraw[(size_t)b * 36864 + idx] = tanhf(a);
}

// ---------------------------------------------------------------------------
// k3_ctx: single-pass fallback (used only if ws too small for wpart).
// ---------------------------------------------------------------------------
__global__ __launch_bounds__(256) void k3_ctx(
    const unsigned short* __restrict__ aggb, const float* __restrict__ cw,
    float* __restrict__ wraw)
{
    __shared__ float sA[64 * 68];
    __shared__ float sW[64 * 68];
    const int t = threadIdx.x;
    const int b = blockIdx.z;
    const int d0 = blockIdx.x * 64;
    const int l0 = blockIdx.y * 64;
    const unsigned short* ab = aggb + (size_t)b * 2048 * 192;
    const int ti = t >> 4, tj = t & 15;
    float acc[4][4] = {{0.f}};

    for (int o0 = 0; o0 < 2048; o0 += 64) {
        for (int i = t; i < 4096; i += 256) {
            int oo = i >> 6, dd = i & 63;
            sA[oo * 68 + dd] = bf2f(ab[(size_t)(o0 + oo) * 192 + d0 + dd]);
            sW[oo * 68 + dd] = cw[(size_t)(o0 + oo) * 192 + l0 + dd];
        }
        __syncthreads();
        for (int o = 0; o < 64; ++o) {
            const float* ap = sA + o * 68 + ti * 4;
            const float* wp = sW + o * 68 + tj * 4;
            float a0 = ap[0], a1 = ap[1], a2 = ap[2], a3 = ap[3];
            float w0 = wp[0], w1v = wp[1], w2v = wp[2], w3 = wp[3];
            acc[0][0] = fmaf(a0, w0, acc[0][0]); acc[0][1] = fmaf(a0, w1v, acc[0][1]);
            acc[0][2] = fmaf(a0, w2v, acc[0][2]); acc[0][3] = fmaf(a0, w3, acc[0][3]);
            acc[1][0] = fmaf(a1, w0, acc[1][0]); acc[1][1] = fmaf(a1, w1v, acc[1][1]);
            acc[1][2] = fmaf(a1, w2v, acc[1][2]); acc[1][3] = fmaf(a1, w3, acc[1][3]);
            acc[2][0] = fmaf(a2, w0, acc[2][0]); acc[2][1] = fmaf(a2, w1v, acc[2][1]);
            acc[2][2] = fmaf(a2, w2v, acc[2][2]); acc[2][3] = fmaf(a2, w3, acc[2][3]);
            acc[3][0] = fmaf(a3, w0, acc[3][0]); acc[3][1] = fmaf(a3, w1v, acc[3][1]);
            acc[3][2] = fmaf(a3, w2v, acc[3][2]); acc[3][3] = fmaf(a3, w3, acc[3][3]);
        }
        __syncthreads();
    }
    float* wb = wraw + (size_t)b * 36864;
    #pragma unroll
    for (int i = 0; i < 4; ++i)
        #pragma unroll
        for (int j = 0; j < 4; ++j)
            wb[(d0 + ti * 4 + i) * 192 + l0 + tj * 4 + j] = tanhf(acc[i][j]);
}

// ---------------------------------------------------------------------------
// k3b_m2: 2-deep register pipeline (8 loads in flight).
// ---------------------------------------------------------------------------
__global__ __launch_bounds__(192) void k3b_m2(
    const float* __restrict__ wmat, const float* __restrict__ wl,
    float* __restrict__ m2)
{
    const int t = threadIdx.x;
    const int b = blockIdx.y;
    const int d = blockIdx.x * 2 + (t / 96);
    const int l = t % 96;
    const float* wrow = wmat + (size_t)b * 36864 + d * 192;
    float acc = wl[d * 96 + l];
    float pa[8], pb[8];
    #pragma unroll
    for (int u = 0; u < 8; ++u) { pa[u] = wrow[u]; pb[u] = wl[u * 96 + l]; }
    for (int k0 = 0; k0 < 192; k0 += 8) {
        float ca[8], cb[8];
        #pragma unroll
        for (int u = 0; u < 8; ++u) { ca[u] = pa[u]; cb[u] = pb[u]; }
        const int kn = k0 + 8;
        if (kn < 192) {
            #pragma unroll
            for (int u = 0; u < 8; ++u) {
                pa[u] = wrow[kn + u];
                pb[u] = wl[(kn + u) * 96 + l];
            }
        }
        #pragma unroll
        for (int u = 0; u < 8; ++u) acc = fmaf(ca[u], cb[u], acc);
    }
    m2[(size_t)b * 18432 + d * 96 + l] = acc;
}

// ---------------------------------------------------------------------------
// k4_tiled: out = gcn@M2 + bl. 64 rows x 96 cols per block (grid 32x16,
// 192 thr). m2 staged once in LDS (73.7 KB -> 2 blocks/CU).
// ---------------------------------------------------------------------------
__global__ __launch_bounds__(192) void k4_tiled(
    const float* __restrict__ x, const unsigned short* __restrict__ vt,
    const float* __restrict__ m2, const float* __restrict__ bl,
    float* __restrict__ out)
{
    __shared__ float sm2[192 * 96];
    const int t = threadIdx.x;           // 0..191
    const int rblk = blockIdx.x;         // 0..31
    const int b = blockIdx.y;
    {
        const float4* src = (const float4*)(m2 + (size_t)b * 18432);
        float4* dst = (float4*)sm2;
        #pragma unroll
        for (int i = 0; i < 24; ++i) dst[t + i * 192] = src[t + i * 192];
    }
    __syncthreads();

    const int rg = t / 12;               // 0..15
    const int cg = t % 12;               // 0..11
    const int j0 = cg * 8;
    const int cloc = rblk * 64 + rg * 4; // within-batch row
    const int rr = b * 2048 + cloc;      // global row
    float acc[4][8];
    #pragma unroll
    for (int i = 0; i < 4; ++i)
        #pragma unroll
        for (int j = 0; j < 8; ++j) acc[i][j] = bl[j0 + j];

    for (int k0 = 0; k0 < 128; k0 += 8) {
        float rv[4][8];
        #pragma unroll
        for (int i = 0; i < 4; ++i) {
            const float4* xr = (const float4*)(x + (size_t)(rr + i) * 128 + k0);
            float4 a = xr[0], c4 = xr[1];
            rv[i][0] = a.x; rv[i][1] = a.y; rv[i][2] = a.z; rv[i][3] = a.w;
            rv[i][4] = c4.x; rv[i][5] = c4.y; rv[i][6] = c4.z; rv[i][7] = c4.w;
        }
        #pragma unroll
        for (int kk = 0; kk < 8; ++kk) {
            const float* mr = sm2 + (k0 + kk) * 96 + j0;
            float mv[8];
            #pragma unroll
            for (int j = 0; j < 8; ++j) mv[j] = mr[j];
            #pragma unroll
            for (int i = 0; i < 4; ++i)
                #pragma unroll
                for (int j = 0; j < 8; ++j)
                    acc[i][j] = fmaf(rv[i][kk], mv[j], acc[i][j]);
        }
    }
    for (int k = 128; k < 192; ++k) {
        const unsigned short* vr = vt + (size_t)(b * 192 + k) * 2048 + cloc;
        float rv0 = bf2f(vr[0]), rv1 = bf2f(vr[1]);
        float rv2 = bf2f(vr[2]), rv3 = bf2f(vr[3]);
        const float* mr = sm2 + k * 96 + j0;
        #pragma unroll
        for (int j = 0; j < 8; ++j) {
            float mv = mr[j];
            acc[0][j] = fmaf(rv0, mv, acc[0][j]);
            acc[1][j] = fmaf(rv1, mv, acc[1][j]);
            acc[2][j] = fmaf(rv2, mv, acc[2][j]);
            acc[3][j] = fmaf(rv3, mv, acc[3][j]);
        }
    }
    #pragma unroll
    for (int i = 0; i < 4; ++i) {
        float* orow = out + (size_t)(rr + i) * 96 + j0;
        *(float4*)orow = make_float4(acc[i][0], acc[i][1], acc[i][2], acc[i][3]);
        *(float4*)(orow + 4) = make_float4(acc[i][4], acc[i][5], acc[i][6], acc[i][7]);
    }
}

// ---------------------------------------------------------------------------
extern "C" void kernel_launch(void* const* d_in, const int* in_sizes, int n_in,
                              void* d_out, int out_size, void* d_ws, size_t ws_size,
                              hipStream_t stream) {
    const float* x      = (const float*)d_in[0];
    const float* id_emb = (const float*)d_in[1];
    const float* w1     = (const float*)d_in[2];
    const float* b1     = (const float*)d_in[3];
    const float* w2     = (const float*)d_in[4];
    const float* b2     = (const float*)d_in[5];
    const float* ce     = (const float*)d_in[6];
    const float* wic    = (const float*)d_in[7];
    const float* bic    = (const float*)d_in[8];
    const float* wg     = (const float*)d_in[9];
    const float* bg     = (const float*)d_in[10];
    const float* cw     = (const float*)d_in[11];
    const float* wl     = (const float*)d_in[12];
    const float* bl     = (const float*)d_in[13];
    float* out = (float*)d_out;

    float* ws = (float*)d_ws;
    unsigned short* vt    = (unsigned short*)ws;             // 3,145,728 f-eq
    unsigned short* geb16 = (unsigned short*)(ws + 3145728); //   524,288 f-eq
    unsigned short* aggb  = (unsigned short*)(ws + 3670016); // 3,145,728 f-eq
    float* wraw  = ws + 6815744;                             //   589,824
    float* m2    = ws + 7405568;                             //   294,912
    float* sumv  = ws + 7700480;                             //     3,072
    float* wpart = ws + 7703552;                             // 4,718,592 (opt)
    unsigned short* cwhi = (unsigned short*)(ws + 12422144); //   196,608 f-eq
    unsigned short* cwlo = cwhi + 393216;                    //   196,608 f-eq
    const size_t need_sk   = (7703552ull + 4718592ull) * 4ull;            // 49.7 MB
    const size_t need_mfma = (7703552ull + 4718592ull + 393216ull) * 4ull; // 51.3 MB
    const bool use_mfma = (ws_size >= need_mfma);
    const bool use_sk   = (ws_size >= need_sk);

    hipLaunchKernelGGL(k0_transpose_x, dim3(32, 16), dim3(256), 0, stream, x, vt);
    hipLaunchKernelGGL(k1_tiled, dim3(1024), dim3(256), 0, stream,
                       x, id_emb, w1, b1, w2, b2, ce, wic, bic, wg, bg, vt, geb16);
    hipLaunchKernelGGL(k1b_sumv, dim3(192, 16), dim3(256), 0, stream, vt, sumv);
    hipLaunchKernelGGL(k2_fused, dim3(32, 16), dim3(512), 0, stream,
                       geb16, vt, sumv, aggb);
    if (use_mfma) {
        hipLaunchKernelGGL(k3a_split, dim3(1536), dim3(256), 0, stream,
                           cw, cwhi, cwlo);
        hipLaunchKernelGGL(k3_mfma_sk, dim3(3, 3, 128), dim3(256), 0, stream,
                           aggb, cwhi, cwlo, wpart);
        hipLaunchKernelGGL(k3r_reduce, dim3(144, 16), dim3(256), 0, stream,
                           wpart, wraw);
    } else if (use_sk) {
        hipLaunchKernelGGL(k3_ctx_sk, dim3(3, 3, 128), dim3(256), 0, stream,
                           aggb, cw, wpart);
        hipLaunchKernelGGL(k3r_reduce, dim3(144, 16), dim3(256), 0, stream,
                           wpart, wraw);
    } else {
        hipLaunchKernelGGL(k3_ctx, dim3(3, 3, 16), dim3(256), 0, stream,
                           aggb, cw, wraw);
    }
    hipLaunchKernelGGL(k3b_m2, dim3(96, 16), dim3(192), 0, stream,
                       wraw, wl, m2);
    hipLaunchKernelGGL(k4_tiled, dim3(32, 16), dim3(192), 0, stream,
                       x, vt, m2, bl, out);
}

// Round 11
// 310.804 us; speedup vs baseline: 1.0914x; 1.0914x over previous
//
#include <hip/hip_runtime.h>
#include <hip/hip_bf16.h>

// B=16, C=2048, T=128, ID=32, NC=16, CD=32, GD=32, OUT=96, GIN=192
// ws (floats): vt(bf16) @0 (3,145,728) | geb16(bf16) @3145728 (524,288) |
// aggb(bf16) @3670016 (3,145,728) | wraw @6815744 (589,824) |
// m2 @7405568 (294,912) | sumv @7700480 (3,072) |
// wpart @7703552 (4,718,592) | cwhi/cwlo(bf16) @12422144 (393,216 f-eq)
//   => 51.3 MB full (30.8 min fallback).
//
// ADJACENCY SEMANTICS: weight(m) = 0 if m==o; exp(s) if s>0; 1 if s<=0.
// Decomposition: d = weight-1 (d=-1 diag, exp(s)-1 if s>0, else 0).
// agg_unnorm = sumV + MFMA(d,V);  l = 2048 + sum(d).
//
// Round-22: k3 -> bf16 MFMA w/ cw hi/lo split: 291.4 -> 274.0 (matched).
// Round-23: k2 48KB single-buffer: FAILED (+3.6us; occupancy grid-capped).
// Round-24: k2 512-thr wave-split: FAILED (VGPR 64, WRITE 121MB = spill,
//           k2 134us). LESSON: never launch_bounds-constrain this family;
//           divergent roles need the UNION of register sets.
// Round-25 (this round):
//  a) k2: byte-exact revert to round-7 verified version (65.8us measured:
//     256 thr, sGeO + dbuf sGe/sVtA, 2 barriers, XCD remap, diag hoist).
//  b) k4: drop the 73.7KB sm2 LDS stage (was 2 blocks/CU = 6 waves/CU TLP
//     starvation). m2 is L2-resident + block-shared; read it directly from
//     global. Same fp32 values & accumulation order -> bit-identical.
// Prediction: k2 -> ~66us (VGPR~104, WRITE~12MB); k4 -> 12-20us;
//   total ~258-272.

typedef __attribute__((ext_vector_type(8))) short short8;
typedef __attribute__((ext_vector_type(16))) float f32x16;

__device__ __forceinline__ unsigned short f2bf(float f) {
    __hip_bfloat16 h = __float2bfloat16(f);
    return *reinterpret_cast<unsigned short*>(&h);
}
__device__ __forceinline__ float bf2f(unsigned short u) {
    __hip_bfloat16 h = *reinterpret_cast<__hip_bfloat16*>(&u);
    return __bfloat162float(h);
}

// ---------------------------------------------------------------------------
// k0: transpose x (fp32 [b][m][128]) -> VT bf16 [b][ch][m] for ch 0..127.
// ---------------------------------------------------------------------------
__global__ __launch_bounds__(256) void k0_transpose_x(
    const float* __restrict__ x, unsigned short* __restrict__ vt)
{
    __shared__ float sT[64 * 133];
    const int t = threadIdx.x;
    const int m0 = blockIdx.x * 64;
    const int b = blockIdx.y;
    const float* xb = x + (size_t)b * 2048 * 128;
    #pragma unroll
    for (int kk = 0; kk < 8; ++kk) {
        int i = t + kk * 256;
        int mm = i >> 5, q4 = i & 31;
        float4 v = ((const float4*)(xb + (size_t)(m0 + mm) * 128))[q4];
        float* d = sT + mm * 133 + q4 * 4;
        d[0] = v.x; d[1] = v.y; d[2] = v.z; d[3] = v.w;
    }
    __syncthreads();
    const int mp = t & 31;
    const int ch0 = t >> 5;
    #pragma unroll
    for (int pass = 0; pass < 16; ++pass) {
        int ch = ch0 + pass * 8;
        unsigned int u0 = f2bf(sT[(2 * mp) * 133 + ch]);
        unsigned int u1 = f2bf(sT[(2 * mp + 1) * 133 + ch]);
        *((unsigned int*)(vt + (size_t)(b * 192 + ch) * 2048 + m0) + mp) =
            u0 | (u1 << 16);
    }
}

// ---------------------------------------------------------------------------
// k1_tiled: 32 rows per block (grid 1024, 256 thr). Phase B reads x directly.
// ---------------------------------------------------------------------------
__global__ __launch_bounds__(256) void k1_tiled(
    const float* __restrict__ x, const float* __restrict__ id_emb,
    const float* __restrict__ w1, const float* __restrict__ b1,
    const float* __restrict__ w2, const float* __restrict__ b2,
    const float* __restrict__ ce, const float* __restrict__ wic,
    const float* __restrict__ bic, const float* __restrict__ wg,
    const float* __restrict__ bg, unsigned short* __restrict__ vt,
    unsigned short* __restrict__ geb16)
{
    __shared__ float sh[32 * 68];
    __shared__ float sid[32 * 36];
    __shared__ float sic[32 * 36];
    __shared__ float scl[32 * 36];
    __shared__ float sp[32 * 20];

    const int t = threadIdx.x;
    const int r0 = blockIdx.x * 32;     // 32-row blocks never cross a batch
    const int b = r0 >> 11;
    const int c0 = r0 & 2047;

    // Phase B: h = relu(xs@w1 + b1). row=t>>3, 8 cols per thread.
    {
        const int row = t >> 3, j0 = (t & 7) * 8;
        const float* xrow = x + (size_t)(r0 + row) * 128;
        float acc[8];
        #pragma unroll
        for (int j = 0; j < 8; ++j) acc[j] = b1[j0 + j];
        float4 pa[4], pb[4];
        float4 pxv;
        #pragma unroll
        for (int u = 0; u < 4; ++u) {
            const float4* wr = (const float4*)(w1 + u * 64 + j0);
            pa[u] = wr[0]; pb[u] = wr[1];
        }
        pxv = *(const float4*)(xrow);
        for (int k0 = 0; k0 < 128; k0 += 4) {
            float4 ca[4], cb[4];
            float4 cxv = pxv;
            #pragma unroll
            for (int u = 0; u < 4; ++u) { ca[u] = pa[u]; cb[u] = pb[u]; }
            const int kn = k0 + 4;
            if (kn < 128) {
                #pragma unroll
                for (int u = 0; u < 4; ++u) {
                    const float4* wr = (const float4*)(w1 + (kn + u) * 64 + j0);
                    pa[u] = wr[0]; pb[u] = wr[1];
                }
                pxv = *(const float4*)(xrow + kn);
            }
            float cx[4] = {cxv.x, cxv.y, cxv.z, cxv.w};
            #pragma unroll
            for (int u = 0; u < 4; ++u) {
                acc[0] = fmaf(cx[u], ca[u].x, acc[0]);
                acc[1] = fmaf(cx[u], ca[u].y, acc[1]);
                acc[2] = fmaf(cx[u], ca[u].z, acc[2]);
                acc[3] = fmaf(cx[u], ca[u].w, acc[3]);
                acc[4] = fmaf(cx[u], cb[u].x, acc[4]);
                acc[5] = fmaf(cx[u], cb[u].y, acc[5]);
                acc[6] = fmaf(cx[u], cb[u].z, acc[6]);
                acc[7] = fmaf(cx[u], cb[u].w, acc[7]);
            }
        }
        float* hr = sh + row * 68 + j0;
        #pragma unroll
        for (int j = 0; j < 8; ++j) hr[j] = fmaxf(acc[j], 0.f);
    }
    __syncthreads();

    // Phase C: ide = id_emb + h@w2 + b2. row=t>>3, 4 cols per thread.
    {
        const int row = t >> 3, j0 = (t & 7) * 4;
        const int c = c0 + row;
        const float* hrow = sh + row * 68;
        float acc[4];
        #pragma unroll
        for (int j = 0; j < 4; ++j) acc[j] = b2[j0 + j];
        float4 pw[4];
        float  ph[4];
        #pragma unroll
        for (int u = 0; u < 4; ++u) {
            pw[u] = *(const float4*)(w2 + u * 32 + j0);
            ph[u] = hrow[u];
        }
        for (int k0 = 0; k0 < 64; k0 += 4) {
            float4 cw4[4];
            float  ch4[4];
            #pragma unroll
            for (int u = 0; u < 4; ++u) { cw4[u] = pw[u]; ch4[u] = ph[u]; }
            const int kn = k0 + 4;
            if (kn < 64) {
                #pragma unroll
                for (int u = 0; u < 4; ++u) {
                    pw[u] = *(const float4*)(w2 + (kn + u) * 32 + j0);
                    ph[u] = hrow[kn + u];
                }
            }
            #pragma unroll
            for (int u = 0; u < 4; ++u) {
                acc[0] = fmaf(ch4[u], cw4[u].x, acc[0]);
                acc[1] = fmaf(ch4[u], cw4[u].y, acc[1]);
                acc[2] = fmaf(ch4[u], cw4[u].z, acc[2]);
                acc[3] = fmaf(ch4[u], cw4[u].w, acc[3]);
            }
        }
        #pragma unroll
        for (int j = 0; j < 4; ++j) {
            float ide = id_emb[c * 32 + j0 + j] + acc[j];
            sid[row * 36 + j0 + j] = ide;
            vt[(size_t)(b * 192 + 128 + j0 + j) * 2048 + c] = f2bf(ide);
        }
    }
    __syncthreads();

    // Phase D: ic = id_e@wic + bic. Same mapping, pipelined.
    {
        const int row = t >> 3, j0 = (t & 7) * 4;
        const float* irow = sid + row * 36;
        float acc[4];
        #pragma unroll
        for (int j = 0; j < 4; ++j) acc[j] = bic[j0 + j];
        float4 pw[4];
        float  pi[4];
        #pragma unroll
        for (int u = 0; u < 4; ++u) {
            pw[u] = *(const float4*)(wic + u * 32 + j0);
            pi[u] = irow[u];
        }
        for (int k0 = 0; k0 < 32; k0 += 4) {
            float4 cw4[4];
            float  ci4[4];
            #pragma unroll
            for (int u = 0; u < 4; ++u) { cw4[u] = pw[u]; ci4[u] = pi[u]; }
            const int kn = k0 + 4;
            if (kn < 32) {
                #pragma unroll
                for (int u = 0; u < 4; ++u) {
                    pw[u] = *(const float4*)(wic + (kn + u) * 32 + j0);
                    pi[u] = irow[kn + u];
                }
            }
            #pragma unroll
            for (int u = 0; u < 4; ++u) {
                acc[0] = fmaf(ci4[u], cw4[u].x, acc[0]);
                acc[1] = fmaf(ci4[u], cw4[u].y, acc[1]);
                acc[2] = fmaf(ci4[u], cw4[u].z, acc[2]);
                acc[3] = fmaf(ci4[u], cw4[u].w, acc[3]);
            }
        }
        #pragma unroll
        for (int j = 0; j < 4; ++j) sic[row * 36 + j0 + j] = acc[j];
    }
    __syncthreads();

    // Phase E: logits. n=t&15, rows t>>4 and (t>>4)+16. Batched loads.
    {
        const int n = t & 15, rowp = t >> 4;
        const float* cer = ce + n * 32;
        float a0 = 0.f, a1 = 0.f;
        #pragma unroll
        for (int k0 = 0; k0 < 32; k0 += 8) {
            float cv[8], s0[8], s1[8];
            #pragma unroll
            for (int u = 0; u < 8; ++u) {
                cv[u] = cer[k0 + u];
                s0[u] = sic[rowp * 36 + k0 + u];
                s1[u] = sic[(rowp + 16) * 36 + k0 + u];
            }
            #pragma unroll
            for (int u = 0; u < 8; ++u) {
                a0 = fmaf(s0[u], cv[u], a0);
                a1 = fmaf(s1[u], cv[u], a1);
            }
        }
        sp[rowp * 20 + n] = a0;
        sp[(rowp + 16) * 20 + n] = a1;
    }
    __syncthreads();

    // Phase F: softmax over 16 clusters, one thread per row (serial).
    if (t < 32) {
        float* pr = sp + t * 20;
        float mx = pr[0];
        for (int n = 1; n < 16; ++n) mx = fmaxf(mx, pr[n]);
        float ss = 0.f;
        for (int n = 0; n < 16; ++n) { float e = __expf(pr[n] - mx); pr[n] = e; ss += e; }
        float inv = 1.f / ss;
        for (int n = 0; n < 16; ++n) pr[n] *= inv;
    }
    __syncthreads();

    // Phase G: cl = p@ce. row=t>>3, 4 cols per thread, pipelined.
    {
        const int row = t >> 3, j0 = (t & 7) * 4;
        const int c = c0 + row;
        const float* prow = sp + row * 20;
        float acc[4] = {0.f, 0.f, 0.f, 0.f};
        float4 pc[4];
        float  pp[4];
        #pragma unroll
        for (int u = 0; u < 4; ++u) {
            pc[u] = *(const float4*)(ce + u * 32 + j0);
            pp[u] = prow[u];
        }
        for (int n0 = 0; n0 < 16; n0 += 4) {
            float4 cc4[4];
            float  cp4[4];
            #pragma unroll
            for (int u = 0; u < 4; ++u) { cc4[u] = pc[u]; cp4[u] = pp[u]; }
            const int nn = n0 + 4;
            if (nn < 16) {
                #pragma unroll
                for (int u = 0; u < 4; ++u) {
                    pc[u] = *(const float4*)(ce + (nn + u) * 32 + j0);
                    pp[u] = prow[nn + u];
                }
            }
            #pragma unroll
            for (int u = 0; u < 4; ++u) {
                acc[0] = fmaf(cp4[u], cc4[u].x, acc[0]);
                acc[1] = fmaf(cp4[u], cc4[u].y, acc[1]);
                acc[2] = fmaf(cp4[u], cc4[u].z, acc[2]);
                acc[3] = fmaf(cp4[u], cc4[u].w, acc[3]);
            }
        }
        #pragma unroll
        for (int j = 0; j < 4; ++j) {
            scl[row * 36 + j0 + j] = acc[j];
            vt[(size_t)(b * 192 + 160 + j0 + j) * 2048 + c] = f2bf(acc[j]);
        }
    }
    __syncthreads();

    // Phase H: ge = [id|cl]@wg + bg -> bf16. Two pipelined 32-loops.
    {
        const int row = t >> 3, j0 = (t & 7) * 4;
        const int r = r0 + row;
        const float* irow = sid + row * 36;
        const float* crow = scl + row * 36;
        float acc[4];
        #pragma unroll
        for (int j = 0; j < 4; ++j) acc[j] = bg[j0 + j];
        // id part
        {
            float4 pw[4];
            float  pi[4];
            #pragma unroll
            for (int u = 0; u < 4; ++u) {
                pw[u] = *(const float4*)(wg + u * 32 + j0);
                pi[u] = irow[u];
            }
            for (int k0 = 0; k0 < 32; k0 += 4) {
                float4 cw4[4];
                float  ci4[4];
                #pragma unroll
                for (int u = 0; u < 4; ++u) { cw4[u] = pw[u]; ci4[u] = pi[u]; }
                const int kn = k0 + 4;
                if (kn < 32) {
                    #pragma unroll
                    for (int u = 0; u < 4; ++u) {
                        pw[u] = *(const float4*)(wg + (kn + u) * 32 + j0);
                        pi[u] = irow[kn + u];
                    }
                }
                #pragma unroll
                for (int u = 0; u < 4; ++u) {
                    acc[0] = fmaf(ci4[u], cw4[u].x, acc[0]);
                    acc[1] = fmaf(ci4[u], cw4[u].y, acc[1]);
                    acc[2] = fmaf(ci4[u], cw4[u].z, acc[2]);
                    acc[3] = fmaf(ci4[u], cw4[u].w, acc[3]);
                }
            }
        }
        // cl part
        {
            float4 pw[4];
            float  pcv[4];
            #pragma unroll
            for (int u = 0; u < 4; ++u) {
                pw[u] = *(const float4*)(wg + (32 + u) * 32 + j0);
                pcv[u] = crow[u];
            }
            for (int k0 = 0; k0 < 32; k0 += 4) {
                float4 cw4[4];
                float  cc4[4];
                #pragma unroll
                for (int u = 0; u < 4; ++u) { cw4[u] = pw[u]; cc4[u] = pcv[u]; }
                const int kn = k0 + 4;
                if (kn < 32) {
                    #pragma unroll
                    for (int u = 0; u < 4; ++u) {
                        pw[u] = *(const float4*)(wg + (32 + kn + u) * 32 + j0);
                        pcv[u] = crow[kn + u];
                    }
                }
                #pragma unroll
                for (int u = 0; u < 4; ++u) {
                    acc[0] = fmaf(cc4[u], cw4[u].x, acc[0]);
                    acc[1] = fmaf(cc4[u], cw4[u].y, acc[1]);
                    acc[2] = fmaf(cc4[u], cw4[u].z, acc[2]);
                    acc[3] = fmaf(cc4[u], cw4[u].w, acc[3]);
                }
            }
        }
        #pragma unroll
        for (int j = 0; j < 4; ++j)
            geb16[(size_t)r * 32 + j0 + j] = f2bf(acc[j]);
    }
}

// ---------------------------------------------------------------------------
// k1b: sumV[b][ch] = sum_m VT[b][ch][m] (fp32 accumulate of bf16).
// ---------------------------------------------------------------------------
__global__ __launch_bounds__(256) void k1b_sumv(
    const unsigned short* __restrict__ vt, float* __restrict__ sumv)
{
    __shared__ float red[256];
    const int ch = blockIdx.x, b = blockIdx.y, t = threadIdx.x;
    const unsigned short* row = vt + (size_t)(b * 192 + ch) * 2048;
    float a = 0.f;
    #pragma unroll
    for (int j = 0; j < 8; ++j) a += bf2f(row[t * 8 + j]);
    red[t] = a; __syncthreads();
    for (int off = 128; off > 0; off >>= 1) {
        if (t < off) red[t] += red[t + off];
        __syncthreads();
    }
    if (t == 0) sumv[b * 192 + ch] = red[0];
}

// ---------------------------------------------------------------------------
// k2: all-MFMA core. Round-25: byte-exact revert to the round-7 verified
// version (65.8us): 256 thr, sGeO + dbuf sGe/sVtA + reg prefetch,
// 2 barriers/iter, XCD remap, diag hoist. Linear LDS.
// ---------------------------------------------------------------------------
__global__ __launch_bounds__(256) void k2_fused(
    const unsigned short* __restrict__ geb16,
    const unsigned short* __restrict__ vt,
    const float* __restrict__ sumv,
    unsigned short* __restrict__ aggb)
{
    __shared__ unsigned short sGeO[64 * 40];
    __shared__ unsigned short sGe[2][64 * 40];
    __shared__ unsigned short sVtA[2][192 * 72];
    __shared__ unsigned short dw[64 * 72];
    __shared__ float s_sum[192];
    __shared__ float sinv[64];
    float* lpbuf = (float*)sVtA;   // [64][68] fp32, used only after main loop

    const int t = threadIdx.x;
    // XCD-bijective remap: 512 blocks = 8 XCDs x 64. XCD x gets contiguous
    // chunk -> 2 batches per XCD -> vt working set 1.5MB < 4MB XCD-L2.
    const int lin = blockIdx.x + gridDim.x * blockIdx.y;   // 0..511
    const int nb = (lin & 7) * 64 + (lin >> 3);
    const int o0 = (nb & 31) * 64;
    const int b = nb >> 5;
    const unsigned short* geb = geb16 + (size_t)b * 2048 * 32;
    const unsigned short* vtb = vt + (size_t)b * 192 * 2048;

    const int lane = t & 63;
    const int mg = t >> 6;
    const int col = lane & 31;
    const int grp = lane >> 5;
    const int os = (mg & 1) * 32;
    const int ms = (mg >> 1) * 32;
    const int orow0 = (mg & 1) * 32;
    const int dbase = (mg >> 1) * 96;

    const int ge_row = t >> 2, ge_c8 = t & 3;

    short8 rGe;
    short8 rVt0, rVt1, rVt2, rVt3, rVt4, rVt5;

    if (t < 192) s_sum[t] = sumv[b * 192 + t];
    {
        short8 v = *(const short8*)(geb + (size_t)(o0 + ge_row) * 32 + ge_c8 * 8);
        *(short8*)(sGeO + ge_row * 40 + ge_c8 * 8) = v;
    }
    {
        rGe = *(const short8*)(geb + (size_t)ge_row * 32 + ge_c8 * 8);
        int i0;
        i0 = t + 0 * 256; rVt0 = *(const short8*)(vtb + (size_t)(i0 >> 3) * 2048 + 0 + (i0 & 7) * 8);
        i0 = t + 1 * 256; rVt1 = *(const short8*)(vtb + (size_t)(i0 >> 3) * 2048 + 0 + (i0 & 7) * 8);
        i0 = t + 2 * 256; rVt2 = *(const short8*)(vtb + (size_t)(i0 >> 3) * 2048 + 0 + (i0 & 7) * 8);
        i0 = t + 3 * 256; rVt3 = *(const short8*)(vtb + (size_t)(i0 >> 3) * 2048 + 0 + (i0 & 7) * 8);
        i0 = t + 4 * 256; rVt4 = *(const short8*)(vtb + (size_t)(i0 >> 3) * 2048 + 0 + (i0 & 7) * 8);
        i0 = t + 5 * 256; rVt5 = *(const short8*)(vtb + (size_t)(i0 >> 3) * 2048 + 0 + (i0 & 7) * 8);
    }
    {
        *(short8*)(sGe[0] + ge_row * 40 + ge_c8 * 8) = rGe;
        int i0;
        i0 = t + 0 * 256; *(short8*)(sVtA[0] + (i0 >> 3) * 72 + (i0 & 7) * 8) = rVt0;
        i0 = t + 1 * 256; *(short8*)(sVtA[0] + (i0 >> 3) * 72 + (i0 & 7) * 8) = rVt1;
        i0 = t + 2 * 256; *(short8*)(sVtA[0] + (i0 >> 3) * 72 + (i0 & 7) * 8) = rVt2;
        i0 = t + 3 * 256; *(short8*)(sVtA[0] + (i0 >> 3) * 72 + (i0 & 7) * 8) = rVt3;
        i0 = t + 4 * 256; *(short8*)(sVtA[0] + (i0 >> 3) * 72 + (i0 & 7) * 8) = rVt4;
        i0 = t + 5 * 256; *(short8*)(sVtA[0] + (i0 >> 3) * 72 + (i0 & 7) * 8) = rVt5;
    }
    __syncthreads();

    f32x16 acc0, acc1, acc2;
    #pragma unroll
    for (int i = 0; i < 16; ++i) { acc0[i] = 0.f; acc1[i] = 0.f; acc2[i] = 0.f; }
    float lpA[16];
    #pragma unroll
    for (int i = 0; i < 16; ++i) lpA[i] = 0.f;

    int cur = 0;
    for (int m0 = 0; m0 < 2048; m0 += 64) {
        const bool have_next = (m0 + 64 < 2048);

        if (have_next) {
            const int mn = m0 + 64;
            rGe = *(const short8*)(geb + (size_t)(mn + ge_row) * 32 + ge_c8 * 8);
            int i0;
            i0 = t + 0 * 256; rVt0 = *(const short8*)(vtb + (size_t)(i0 >> 3) * 2048 + mn + (i0 & 7) * 8);
            i0 = t + 1 * 256; rVt1 = *(const short8*)(vtb + (size_t)(i0 >> 3) * 2048 + mn + (i0 & 7) * 8);
            i0 = t + 2 * 256; rVt2 = *(const short8*)(vtb + (size_t)(i0 >> 3) * 2048 + mn + (i0 & 7) * 8);
            i0 = t + 3 * 256; rVt3 = *(const short8*)(vtb + (size_t)(i0 >> 3) * 2048 + mn + (i0 & 7) * 8);
            i0 = t + 4 * 256; rVt4 = *(const short8*)(vtb + (size_t)(i0 >> 3) * 2048 + mn + (i0 & 7) * 8);
            i0 = t + 5 * 256; rVt5 = *(const short8*)(vtb + (size_t)(i0 >> 3) * 2048 + mn + (i0 & 7) * 8);
        }

        f32x16 sacc;
        #pragma unroll
        for (int i = 0; i < 16; ++i) sacc[i] = 0.f;
        #pragma unroll
        for (int ks = 0; ks < 2; ++ks) {
            short8 A  = *(const short8*)(sGeO + (os + col) * 40 + ks * 16 + grp * 8);
            short8 Bf = *(const short8*)(sGe[cur] + (ms + col) * 40 + ks * 16 + grp * 8);
            sacc = __builtin_amdgcn_mfma_f32_32x32x16_bf16(A, Bf, sacc, 0, 0, 0);
        }
        {
            const int m_local = ms + col;
            if (m0 != o0) {              // no diagonal in this tile
                #pragma unroll
                for (int r = 0; r < 16; ++r) {
                    int o_local = os + (r & 3) + 8 * (r >> 2) + 4 * grp;
                    float s = sacc[r];
                    float d = (s > 0.f) ? (__expf(s) - 1.f) : 0.f;
                    lpA[r] += d;
                    dw[o_local * 72 + m_local] = f2bf(d);
                }
            } else {
                const int gm = m0 + m_local;
                #pragma unroll
                for (int r = 0; r < 16; ++r) {
                    int o_local = os + (r & 3) + 8 * (r >> 2) + 4 * grp;
                    float s = sacc[r];
                    float d = (gm == o0 + o_local) ? -1.f
                            : ((s > 0.f) ? (__expf(s) - 1.f) : 0.f);
                    lpA[r] += d;
                    dw[o_local * 72 + m_local] = f2bf(d);
                }
            }
        }
        __syncthreads();   // dw ready

        #pragma unroll
        for (int ks = 0; ks < 4; ++ks) {
            short8 A  = *(const short8*)(dw + (orow0 + col) * 72 + ks * 16 + grp * 8);
            short8 B0 = *(const short8*)(sVtA[cur] + (dbase + col) * 72 + ks * 16 + grp * 8);
            short8 B1 = *(const short8*)(sVtA[cur] + (dbase + 32 + col) * 72 + ks * 16 + grp * 8);
            short8 B2 = *(const short8*)(sVtA[cur] + (dbase + 64 + col) * 72 + ks * 16 + grp * 8);
            acc0 = __builtin_amdgcn_mfma_f32_32x32x16_bf16(A, B0, acc0, 0, 0, 0);
            acc1 = __builtin_amdgcn_mfma_f32_32x32x16_bf16(A, B1, acc1, 0, 0, 0);
            acc2 = __builtin_amdgcn_mfma_f32_32x32x16_bf16(A, B2, acc2, 0, 0, 0);
        }

        if (have_next) {
            const int nbuf = cur ^ 1;
            *(short8*)(sGe[nbuf] + ge_row * 40 + ge_c8 * 8) = rGe;
            int i0;
            i0 = t + 0 * 256; *(short8*)(sVtA[nbuf] + (i0 >> 3) * 72 + (i0 & 7) * 8) = rVt0;
            i0 = t + 1 * 256; *(short8*)(sVtA[nbuf] + (i0 >> 3) * 72 + (i0 & 7) * 8) = rVt1;
            i0 = t + 2 * 256; *(short8*)(sVtA[nbuf] + (i0 >> 3) * 72 + (i0 & 7) * 8) = rVt2;
            i0 = t + 3 * 256; *(short8*)(sVtA[nbuf] + (i0 >> 3) * 72 + (i0 & 7) * 8) = rVt3;
            i0 = t + 4 * 256; *(short8*)(sVtA[nbuf] + (i0 >> 3) * 72 + (i0 & 7) * 8) = rVt4;
            i0 = t + 5 * 256; *(short8*)(sVtA[nbuf] + (i0 >> 3) * 72 + (i0 & 7) * 8) = rVt5;
        }
        __syncthreads();
        cur ^= 1;
    }

    {
        const int widx = mg >> 1;
        #pragma unroll
        for (int r = 0; r < 16; ++r) {
            int ol = os + (r & 3) + 8 * (r >> 2) + 4 * grp;
            lpbuf[(widx * 32 + col) * 68 + ol] = lpA[r];
        }
    }
    __syncthreads();
    if (t < 64) {
        float l = 2048.f;
        for (int i = 0; i < 64; ++i) l += lpbuf[i * 68 + t];
        sinv[t] = 1.f / l;
    }
    __syncthreads();

    {
        f32x16 av[3] = {acc0, acc1, acc2};
        unsigned short* ab = aggb + (size_t)b * 2048 * 192;
        #pragma unroll
        for (int n = 0; n < 3; ++n) {
            int chn = dbase + n * 32 + col;
            float sv = s_sum[chn];
            #pragma unroll
            for (int r = 0; r < 16; ++r) {
                int ol = orow0 + (r & 3) + 8 * (r >> 2) + 4 * grp;
                ab[(size_t)(o0 + ol) * 192 + chn] =
                    f2bf((sv + av[n][r]) * sinv[ol]);
            }
        }
    }
}

// ---------------------------------------------------------------------------
// k3a_split: cw (fp32 [2048][192]) -> cwhi + cwlo (bf16 each).
// ---------------------------------------------------------------------------
__global__ __launch_bounds__(256) void k3a_split(
    const float* __restrict__ cw, unsigned short* __restrict__ cwhi,
    unsigned short* __restrict__ cwlo)
{
    const int idx = blockIdx.x * 256 + threadIdx.x;   // grid 1536 -> 393216
    float v = cw[idx];
    unsigned short h = f2bf(v);
    cwhi[idx] = h;
    cwlo[idx] = f2bf(v - bf2f(h));
}

// ---------------------------------------------------------------------------
// k3_mfma_sk: wpart[slot][d][l] = sum_{o in ks-range} agg[o][d]*cw[o][l]
// via bf16 MFMA with cw hi/lo split. No LDS, no barriers.
// ---------------------------------------------------------------------------
__global__ __launch_bounds__(256) void k3_mfma_sk(
    const unsigned short* __restrict__ aggb,
    const unsigned short* __restrict__ cwhi,
    const unsigned short* __restrict__ cwlo,
    float* __restrict__ wpart)
{
    const int t = threadIdx.x;
    const int slot = blockIdx.z;
    const int b = slot >> 3;
    const int ks = slot & 7;
    const int d0 = blockIdx.x * 64;
    const int l0 = blockIdx.y * 64;
    const unsigned short* ab = aggb + (size_t)b * 2048 * 192;

    const int lane = t & 63;
    const int w = t >> 6;
    const int col = lane & 31;
    const int grp = lane >> 5;
    const int drow = d0 + (w & 1) * 32 + col;    // A row for this lane
    const int lrow = l0 + (w >> 1) * 32 + col;   // B row for this lane

    f32x16 acc;
    #pragma unroll
    for (int i = 0; i < 16; ++i) acc[i] = 0.f;

    const int obase = ks * 256;
    #pragma unroll 4
    for (int ostep = 0; ostep < 16; ++ostep) {
        const int ob = obase + ostep * 16 + grp * 8;
        short8 A, Bh, Bl;
        #pragma unroll
        for (int i = 0; i < 8; ++i) {
            const size_t ro = (size_t)(ob + i) * 192;
            A[i]  = (short)ab[ro + drow];
            Bh[i] = (short)cwhi[ro + lrow];
            Bl[i] = (short)cwlo[ro + lrow];
        }
        acc = __builtin_amdgcn_mfma_f32_32x32x16_bf16(A, Bh, acc, 0, 0, 0);
        acc = __builtin_amdgcn_mfma_f32_32x32x16_bf16(A, Bl, acc, 0, 0, 0);
    }

    float* wp = wpart + (size_t)slot * 36864;
    const int lcol = l0 + (w >> 1) * 32 + col;
    #pragma unroll
    for (int r = 0; r < 16; ++r) {
        int dl = d0 + (w & 1) * 32 + (r & 3) + 8 * (r >> 2) + 4 * grp;
        wp[(size_t)dl * 192 + lcol] = acc[r];
    }
}

// ---------------------------------------------------------------------------
// k3_ctx_sk: split-K partial of w-sum (fp32 fallback). blockIdx.z = b*8+ks.
// ---------------------------------------------------------------------------
__global__ __launch_bounds__(256) void k3_ctx_sk(
    const unsigned short* __restrict__ aggb, const float* __restrict__ cw,
    float* __restrict__ wpart)
{
    __shared__ float sA[64 * 68];
    __shared__ float sW[64 * 68];
    const int t = threadIdx.x;
    const int slot = blockIdx.z;
    const int b = slot >> 3;
    const int ks = slot & 7;
    const int d0 = blockIdx.x * 64;
    const int l0 = blockIdx.y * 64;
    const unsigned short* ab = aggb + (size_t)b * 2048 * 192;
    const int ti = t >> 4, tj = t & 15;
    float acc[4][4] = {{0.f}};

    for (int o0 = ks * 256; o0 < ks * 256 + 256; o0 += 64) {
        for (int i = t; i < 4096; i += 256) {
            int oo = i >> 6, dd = i & 63;
            sA[oo * 68 + dd] = bf2f(ab[(size_t)(o0 + oo) * 192 + d0 + dd]);
            sW[oo * 68 + dd] = cw[(size_t)(o0 + oo) * 192 + l0 + dd];
        }
        __syncthreads();
        for (int o = 0; o < 64; ++o) {
            const float* ap = sA + o * 68 + ti * 4;
            const float* wp = sW + o * 68 + tj * 4;
            float a0 = ap[0], a1 = ap[1], a2 = ap[2], a3 = ap[3];
            float w0 = wp[0], w1v = wp[1], w2v = wp[2], w3 = wp[3];
            acc[0][0] = fmaf(a0, w0, acc[0][0]); acc[0][1] = fmaf(a0, w1v, acc[0][1]);
            acc[0][2] = fmaf(a0, w2v, acc[0][2]); acc[0][3] = fmaf(a0, w3, acc[0][3]);
            acc[1][0] = fmaf(a1, w0, acc[1][0]); acc[1][1] = fmaf(a1, w1v, acc[1][1]);
            acc[1][2] = fmaf(a1, w2v, acc[1][2]); acc[1][3] = fmaf(a1, w3, acc[1][3]);
            acc[2][0] = fmaf(a2, w0, acc[2][0]); acc[2][1] = fmaf(a2, w1v, acc[2][1]);
            acc[2][2] = fmaf(a2, w2v, acc[2][2]); acc[2][3] = fmaf(a2, w3, acc[2][3]);
            acc[3][0] = fmaf(a3, w0, acc[3][0]); acc[3][1] = fmaf(a3, w1v, acc[3][1]);
            acc[3][2] = fmaf(a3, w2v, acc[3][2]); acc[3][3] = fmaf(a3, w3, acc[3][3]);
        }
        __syncthreads();
    }
    float* wp = wpart + (size_t)slot * 36864;
    #pragma unroll
    for (int i = 0; i < 4; ++i)
        #pragma unroll
        for (int j = 0; j < 4; ++j)
            wp[(d0 + ti * 4 + i) * 192 + l0 + tj * 4 + j] = acc[i][j];
}

// ---------------------------------------------------------------------------
__global__ __launch_bounds__(256) void k3r_reduce(
    const float* __restrict__ wpart, float* __restrict__ wraw)
{
    const int idx = blockIdx.x * 256 + threadIdx.x;
    const int b = blockIdx.y;
    const float* base = wpart + (size_t)b * 8 * 36864 + idx;
    float a = 0.f;
    #pragma unroll
    for (int ks = 0; ks < 8; ++ks) a += base[(size_t)ks * 36864];
    wraw[(size_t)b * 36864 + idx] = tanhf(a);
}

// ---------------------------------------------------------------------------
// k3_ctx: single-pass fallback (used only if ws too small for wpart).
// ---------------------------------------------------------------------------
__global__ __launch_bounds__(256) void k3_ctx(
    const unsigned short* __restrict__ aggb, const float* __restrict__ cw,
    float* __restrict__ wraw)
{
    __shared__ float sA[64 * 68];
    __shared__ float sW[64 * 68];
    const int t = threadIdx.x;
    const int b = blockIdx.z;
    const int d0 = blockIdx.x * 64;
    const int l0 = blockIdx.y * 64;
    const unsigned short* ab = aggb + (size_t)b * 2048 * 192;
    const int ti = t >> 4, tj = t & 15;
    float acc[4][4] = {{0.f}};

    for (int o0 = 0; o0 < 2048; o0 += 64) {
        for (int i = t; i < 4096; i += 256) {
            int oo = i >> 6, dd = i & 63;
            sA[oo * 68 + dd] = bf2f(ab[(size_t)(o0 + oo) * 192 + d0 + dd]);
            sW[oo * 68 + dd] = cw[(size_t)(o0 + oo) * 192 + l0 + dd];
        }
        __syncthreads();
        for (int o = 0; o < 64; ++o) {
            const float* ap = sA + o * 68 + ti * 4;
            const float* wp = sW + o * 68 + tj * 4;
            float a0 = ap[0], a1 = ap[1], a2 = ap[2], a3 = ap[3];
            float w0 = wp[0], w1v = wp[1], w2v = wp[2], w3 = wp[3];
            acc[0][0] = fmaf(a0, w0, acc[0][0]); acc[0][1] = fmaf(a0, w1v, acc[0][1]);
            acc[0][2] = fmaf(a0, w2v, acc[0][2]); acc[0][3] = fmaf(a0, w3, acc[0][3]);
            acc[1][0] = fmaf(a1, w0, acc[1][0]); acc[1][1] = fmaf(a1, w1v, acc[1][1]);
            acc[1][2] = fmaf(a1, w2v, acc[1][2]); acc[1][3] = fmaf(a1, w3, acc[1][3]);
            acc[2][0] = fmaf(a2, w0, acc[2][0]); acc[2][1] = fmaf(a2, w1v, acc[2][1]);
            acc[2][2] = fmaf(a2, w2v, acc[2][2]); acc[2][3] = fmaf(a2, w3, acc[2][3]);
            acc[3][0] = fmaf(a3, w0, acc[3][0]); acc[3][1] = fmaf(a3, w1v, acc[3][1]);
            acc[3][2] = fmaf(a3, w2v, acc[3][2]); acc[3][3] = fmaf(a3, w3, acc[3][3]);
        }
        __syncthreads();
    }
    float* wb = wraw + (size_t)b * 36864;
    #pragma unroll
    for (int i = 0; i < 4; ++i)
        #pragma unroll
        for (int j = 0; j < 4; ++j)
            wb[(d0 + ti * 4 + i) * 192 + l0 + tj * 4 + j] = tanhf(acc[i][j]);
}

// ---------------------------------------------------------------------------
// k3b_m2: 2-deep register pipeline (8 loads in flight).
// ---------------------------------------------------------------------------
__global__ __launch_bounds__(192) void k3b_m2(
    const float* __restrict__ wmat, const float* __restrict__ wl,
    float* __restrict__ m2)
{
    const int t = threadIdx.x;
    const int b = blockIdx.y;
    const int d = blockIdx.x * 2 + (t / 96);
    const int l = t % 96;
    const float* wrow = wmat + (size_t)b * 36864 + d * 192;
    float acc = wl[d * 96 + l];
    float pa[8], pb[8];
    #pragma unroll
    for (int u = 0; u < 8; ++u) { pa[u] = wrow[u]; pb[u] = wl[u * 96 + l]; }
    for (int k0 = 0; k0 < 192; k0 += 8) {
        float ca[8], cb[8];
        #pragma unroll
        for (int u = 0; u < 8; ++u) { ca[u] = pa[u]; cb[u] = pb[u]; }
        const int kn = k0 + 8;
        if (kn < 192) {
            #pragma unroll
            for (int u = 0; u < 8; ++u) {
                pa[u] = wrow[kn + u];
                pb[u] = wl[(kn + u) * 96 + l];
            }
        }
        #pragma unroll
        for (int u = 0; u < 8; ++u) acc = fmaf(ca[u], cb[u], acc);
    }
    m2[(size_t)b * 18432 + d * 96 + l] = acc;
}

// ---------------------------------------------------------------------------
// k4_tiled: out = gcn@M2 + bl. Round-25: sm2 LDS stage REMOVED (was
// 73.7KB -> 2 blocks/CU = 6 waves/CU TLP starvation). m2 is L2-resident
// and shared by all 16 blocks of a batch -> read directly from global.
// Same fp32 values and accumulation order -> bit-identical output.
// ---------------------------------------------------------------------------
__global__ __launch_bounds__(192) void k4_tiled(
    const float* __restrict__ x, const unsigned short* __restrict__ vt,
    const float* __restrict__ m2, const float* __restrict__ bl,
    float* __restrict__ out)
{
    const int t = threadIdx.x;           // 0..191
    const int rblk = blockIdx.x;         // 0..31
    const int b = blockIdx.y;
    const float* m2b = m2 + (size_t)b * 18432;

    const int rg = t / 12;               // 0..15
    const int cg = t % 12;               // 0..11
    const int j0 = cg * 8;
    const int cloc = rblk * 64 + rg * 4; // within-batch row
    const int rr = b * 2048 + cloc;      // global row
    float acc[4][8];
    #pragma unroll
    for (int i = 0; i < 4; ++i)
        #pragma unroll
        for (int j = 0; j < 8; ++j) acc[i][j] = bl[j0 + j];

    for (int k0 = 0; k0 < 128; k0 += 8) {
        float rv[4][8];
        #pragma unroll
        for (int i = 0; i < 4; ++i) {
            const float4* xr = (const float4*)(x + (size_t)(rr + i) * 128 + k0);
            float4 a = xr[0], c4 = xr[1];
            rv[i][0] = a.x; rv[i][1] = a.y; rv[i][2] = a.z; rv[i][3] = a.w;
            rv[i][4] = c4.x; rv[i][5] = c4.y; rv[i][6] = c4.z; rv[i][7] = c4.w;
        }
        #pragma unroll
        for (int kk = 0; kk < 8; ++kk) {
            const float* mr = m2b + (k0 + kk) * 96 + j0;
            float mv[8];
            #pragma unroll
            for (int j = 0; j < 8; ++j) mv[j] = mr[j];
            #pragma unroll
            for (int i = 0; i < 4; ++i)
                #pragma unroll
                for (int j = 0; j < 8; ++j)
                    acc[i][j] = fmaf(rv[i][kk], mv[j], acc[i][j]);
        }
    }
    for (int k = 128; k < 192; ++k) {
        const unsigned short* vr = vt + (size_t)(b * 192 + k) * 2048 + cloc;
        float rv0 = bf2f(vr[0]), rv1 = bf2f(vr[1]);
        float rv2 = bf2f(vr[2]), rv3 = bf2f(vr[3]);
        const float* mr = m2b + k * 96 + j0;
        #pragma unroll
        for (int j = 0; j < 8; ++j) {
            float mv = mr[j];
            acc[0][j] = fmaf(rv0, mv, acc[0][j]);
            acc[1][j] = fmaf(rv1, mv, acc[1][j]);
            acc[2][j] = fmaf(rv2, mv, acc[2][j]);
            acc[3][j] = fmaf(rv3, mv, acc[3][j]);
        }
    }
    #pragma unroll
    for (int i = 0; i < 4; ++i) {
        float* orow = out + (size_t)(rr + i) * 96 + j0;
        *(float4*)orow = make_float4(acc[i][0], acc[i][1], acc[i][2], acc[i][3]);
        *(float4*)(orow + 4) = make_float4(acc[i][4], acc[i][5], acc[i][6], acc[i][7]);
    }
}

// ---------------------------------------------------------------------------
extern "C" void kernel_launch(void* const* d_in, const int* in_sizes, int n_in,
                              void* d_out, int out_size, void* d_ws, size_t ws_size,
                              hipStream_t stream) {
    const float* x      = (const float*)d_in[0];
    const float* id_emb = (const float*)d_in[1];
    const float* w1     = (const float*)d_in[2];
    const float* b1     = (const float*)d_in[3];
    const float* w2     = (const float*)d_in[4];
    const float* b2     = (const float*)d_in[5];
    const float* ce     = (const float*)d_in[6];
    const float* wic    = (const float*)d_in[7];
    const float* bic    = (const float*)d_in[8];
    const float* wg     = (const float*)d_in[9];
    const float* bg     = (const float*)d_in[10];
    const float* cw     = (const float*)d_in[11];
    const float* wl     = (const float*)d_in[12];
    const float* bl     = (const float*)d_in[13];
    float* out = (float*)d_out;

    float* ws = (float*)d_ws;
    unsigned short* vt    = (unsigned short*)ws;             // 3,145,728 f-eq
    unsigned short* geb16 = (unsigned short*)(ws + 3145728); //   524,288 f-eq
    unsigned short* aggb  = (unsigned short*)(ws + 3670016); // 3,145,728 f-eq
    float* wraw  = ws + 6815744;                             //   589,824
    float* m2    = ws + 7405568;                             //   294,912
    float* sumv  = ws + 7700480;                             //     3,072
    float* wpart = ws + 7703552;                             // 4,718,592 (opt)
    unsigned short* cwhi = (unsigned short*)(ws + 12422144); //   196,608 f-eq
    unsigned short* cwlo = cwhi + 393216;                    //   196,608 f-eq
    const size_t need_sk   = (7703552ull + 4718592ull) * 4ull;            // 49.7 MB
    const size_t need_mfma = (7703552ull + 4718592ull + 393216ull) * 4ull; // 51.3 MB
    const bool use_mfma = (ws_size >= need_mfma);
    const bool use_sk   = (ws_size >= need_sk);

    hipLaunchKernelGGL(k0_transpose_x, dim3(32, 16), dim3(256), 0, stream, x, vt);
    hipLaunchKernelGGL(k1_tiled, dim3(1024), dim3(256), 0, stream,
                       x, id_emb, w1, b1, w2, b2, ce, wic, bic, wg, bg, vt, geb16);
    hipLaunchKernelGGL(k1b_sumv, dim3(192, 16), dim3(256), 0, stream, vt, sumv);
    hipLaunchKernelGGL(k2_fused, dim3(32, 16), dim3(256), 0, stream,
                       geb16, vt, sumv, aggb);
    if (use_mfma) {
        hipLaunchKernelGGL(k3a_split, dim3(1536), dim3(256), 0, stream,
                           cw, cwhi, cwlo);
        hipLaunchKernelGGL(k3_mfma_sk, dim3(3, 3, 128), dim3(256), 0, stream,
                           aggb, cwhi, cwlo, wpart);
        hipLaunchKernelGGL(k3r_reduce, dim3(144, 16), dim3(256), 0, stream,
                           wpart, wraw);
    } else if (use_sk) {
        hipLaunchKernelGGL(k3_ctx_sk, dim3(3, 3, 128), dim3(256), 0, stream,
                           aggb, cw, wpart);
        hipLaunchKernelGGL(k3r_reduce, dim3(144, 16), dim3(256), 0, stream,
                           wpart, wraw);
    } else {
        hipLaunchKernelGGL(k3_ctx, dim3(3, 3, 16), dim3(256), 0, stream,
                           aggb, cw, wraw);
    }
    hipLaunchKernelGGL(k3b_m2, dim3(96, 16), dim3(192), 0, stream,
                       wraw, wl, m2);
    hipLaunchKernelGGL(k4_tiled, dim3(32, 16), dim3(192), 0, stream,
                       x, vt, m2, bl, out);
}

// Round 12
// 271.824 us; speedup vs baseline: 1.2479x; 1.1434x over previous
//
#include <hip/hip_runtime.h>
#include <hip/hip_bf16.h>

// B=16, C=2048, T=128, ID=32, NC=16, CD=32, GD=32, OUT=96, GIN=192
// ws (floats): vt(bf16) @0 (3,145,728) | geb16(bf16) @3145728 (524,288) |
// aggb(bf16) @3670016 (3,145,728) | wraw @6815744 (589,824) |
// m2 @7405568 (294,912) | sumv @7700480 (3,072) |
// wpart @7703552 (4,718,592) | cwhi/cwlo(bf16) @12422144 (393,216 f-eq)
//   => 51.3 MB full (30.8 min fallback).
//
// ADJACENCY SEMANTICS: weight(m) = 0 if m==o; exp(s) if s>0; 1 if s<=0.
// Decomposition: d = weight-1 (d=-1 diag, exp(s)-1 if s>0, else 0).
// agg_unnorm = sumV + MFMA(d,V);  l = 2048 + sum(d).
//
// Round-22: k3 -> bf16 MFMA w/ cw hi/lo split: 291.4 -> 274.0 (matched).
// Round-23/24: k2 structural experiments FAILED (grid-capped occupancy;
//   wave-split spill). Round-25: k2 reverted OK (68.2us) but k4 LDS-stage
//   removal REGRESSED ~34us (dependent m2 loads moved from LDS ~5cy to
//   L1/L2 ~150cy on the critical path). LESSON: scratchpad removal is only
//   free if the replacement access is off the dependence-critical path.
// Round-26 (this round): byte-exact revert of k4 to the round-8 verified
//   LDS-staged version. This reproduces the best harness-verified build
//   (274.0us) exactly. No other changes.
// Prediction: total ~272-278us, absmax 0.0078125.

typedef __attribute__((ext_vector_type(8))) short short8;
typedef __attribute__((ext_vector_type(16))) float f32x16;

__device__ __forceinline__ unsigned short f2bf(float f) {
    __hip_bfloat16 h = __float2bfloat16(f);
    return *reinterpret_cast<unsigned short*>(&h);
}
__device__ __forceinline__ float bf2f(unsigned short u) {
    __hip_bfloat16 h = *reinterpret_cast<__hip_bfloat16*>(&u);
    return __bfloat162float(h);
}

// ---------------------------------------------------------------------------
// k0: transpose x (fp32 [b][m][128]) -> VT bf16 [b][ch][m] for ch 0..127.
// ---------------------------------------------------------------------------
__global__ __launch_bounds__(256) void k0_transpose_x(
    const float* __restrict__ x, unsigned short* __restrict__ vt)
{
    __shared__ float sT[64 * 133];
    const int t = threadIdx.x;
    const int m0 = blockIdx.x * 64;
    const int b = blockIdx.y;
    const float* xb = x + (size_t)b * 2048 * 128;
    #pragma unroll
    for (int kk = 0; kk < 8; ++kk) {
        int i = t + kk * 256;
        int mm = i >> 5, q4 = i & 31;
        float4 v = ((const float4*)(xb + (size_t)(m0 + mm) * 128))[q4];
        float* d = sT + mm * 133 + q4 * 4;
        d[0] = v.x; d[1] = v.y; d[2] = v.z; d[3] = v.w;
    }
    __syncthreads();
    const int mp = t & 31;
    const int ch0 = t >> 5;
    #pragma unroll
    for (int pass = 0; pass < 16; ++pass) {
        int ch = ch0 + pass * 8;
        unsigned int u0 = f2bf(sT[(2 * mp) * 133 + ch]);
        unsigned int u1 = f2bf(sT[(2 * mp + 1) * 133 + ch]);
        *((unsigned int*)(vt + (size_t)(b * 192 + ch) * 2048 + m0) + mp) =
            u0 | (u1 << 16);
    }
}

// ---------------------------------------------------------------------------
// k1_tiled: 32 rows per block (grid 1024, 256 thr). Phase B reads x directly.
// ---------------------------------------------------------------------------
__global__ __launch_bounds__(256) void k1_tiled(
    const float* __restrict__ x, const float* __restrict__ id_emb,
    const float* __restrict__ w1, const float* __restrict__ b1,
    const float* __restrict__ w2, const float* __restrict__ b2,
    const float* __restrict__ ce, const float* __restrict__ wic,
    const float* __restrict__ bic, const float* __restrict__ wg,
    const float* __restrict__ bg, unsigned short* __restrict__ vt,
    unsigned short* __restrict__ geb16)
{
    __shared__ float sh[32 * 68];
    __shared__ float sid[32 * 36];
    __shared__ float sic[32 * 36];
    __shared__ float scl[32 * 36];
    __shared__ float sp[32 * 20];

    const int t = threadIdx.x;
    const int r0 = blockIdx.x * 32;     // 32-row blocks never cross a batch
    const int b = r0 >> 11;
    const int c0 = r0 & 2047;

    // Phase B: h = relu(xs@w1 + b1). row=t>>3, 8 cols per thread.
    {
        const int row = t >> 3, j0 = (t & 7) * 8;
        const float* xrow = x + (size_t)(r0 + row) * 128;
        float acc[8];
        #pragma unroll
        for (int j = 0; j < 8; ++j) acc[j] = b1[j0 + j];
        float4 pa[4], pb[4];
        float4 pxv;
        #pragma unroll
        for (int u = 0; u < 4; ++u) {
            const float4* wr = (const float4*)(w1 + u * 64 + j0);
            pa[u] = wr[0]; pb[u] = wr[1];
        }
        pxv = *(const float4*)(xrow);
        for (int k0 = 0; k0 < 128; k0 += 4) {
            float4 ca[4], cb[4];
            float4 cxv = pxv;
            #pragma unroll
            for (int u = 0; u < 4; ++u) { ca[u] = pa[u]; cb[u] = pb[u]; }
            const int kn = k0 + 4;
            if (kn < 128) {
                #pragma unroll
                for (int u = 0; u < 4; ++u) {
                    const float4* wr = (const float4*)(w1 + (kn + u) * 64 + j0);
                    pa[u] = wr[0]; pb[u] = wr[1];
                }
                pxv = *(const float4*)(xrow + kn);
            }
            float cx[4] = {cxv.x, cxv.y, cxv.z, cxv.w};
            #pragma unroll
            for (int u = 0; u < 4; ++u) {
                acc[0] = fmaf(cx[u], ca[u].x, acc[0]);
                acc[1] = fmaf(cx[u], ca[u].y, acc[1]);
                acc[2] = fmaf(cx[u], ca[u].z, acc[2]);
                acc[3] = fmaf(cx[u], ca[u].w, acc[3]);
                acc[4] = fmaf(cx[u], cb[u].x, acc[4]);
                acc[5] = fmaf(cx[u], cb[u].y, acc[5]);
                acc[6] = fmaf(cx[u], cb[u].z, acc[6]);
                acc[7] = fmaf(cx[u], cb[u].w, acc[7]);
            }
        }
        float* hr = sh + row * 68 + j0;
        #pragma unroll
        for (int j = 0; j < 8; ++j) hr[j] = fmaxf(acc[j], 0.f);
    }
    __syncthreads();

    // Phase C: ide = id_emb + h@w2 + b2. row=t>>3, 4 cols per thread.
    {
        const int row = t >> 3, j0 = (t & 7) * 4;
        const int c = c0 + row;
        const float* hrow = sh + row * 68;
        float acc[4];
        #pragma unroll
        for (int j = 0; j < 4; ++j) acc[j] = b2[j0 + j];
        float4 pw[4];
        float  ph[4];
        #pragma unroll
        for (int u = 0; u < 4; ++u) {
            pw[u] = *(const float4*)(w2 + u * 32 + j0);
            ph[u] = hrow[u];
        }
        for (int k0 = 0; k0 < 64; k0 += 4) {
            float4 cw4[4];
            float  ch4[4];
            #pragma unroll
            for (int u = 0; u < 4; ++u) { cw4[u] = pw[u]; ch4[u] = ph[u]; }
            const int kn = k0 + 4;
            if (kn < 64) {
                #pragma unroll
                for (int u = 0; u < 4; ++u) {
                    pw[u] = *(const float4*)(w2 + (kn + u) * 32 + j0);
                    ph[u] = hrow[kn + u];
                }
            }
            #pragma unroll
            for (int u = 0; u < 4; ++u) {
                acc[0] = fmaf(ch4[u], cw4[u].x, acc[0]);
                acc[1] = fmaf(ch4[u], cw4[u].y, acc[1]);
                acc[2] = fmaf(ch4[u], cw4[u].z, acc[2]);
                acc[3] = fmaf(ch4[u], cw4[u].w, acc[3]);
            }
        }
        #pragma unroll
        for (int j = 0; j < 4; ++j) {
            float ide = id_emb[c * 32 + j0 + j] + acc[j];
            sid[row * 36 + j0 + j] = ide;
            vt[(size_t)(b * 192 + 128 + j0 + j) * 2048 + c] = f2bf(ide);
        }
    }
    __syncthreads();

    // Phase D: ic = id_e@wic + bic. Same mapping, pipelined.
    {
        const int row = t >> 3, j0 = (t & 7) * 4;
        const float* irow = sid + row * 36;
        float acc[4];
        #pragma unroll
        for (int j = 0; j < 4; ++j) acc[j] = bic[j0 + j];
        float4 pw[4];
        float  pi[4];
        #pragma unroll
        for (int u = 0; u < 4; ++u) {
            pw[u] = *(const float4*)(wic + u * 32 + j0);
            pi[u] = irow[u];
        }
        for (int k0 = 0; k0 < 32; k0 += 4) {
            float4 cw4[4];
            float  ci4[4];
            #pragma unroll
            for (int u = 0; u < 4; ++u) { cw4[u] = pw[u]; ci4[u] = pi[u]; }
            const int kn = k0 + 4;
            if (kn < 32) {
                #pragma unroll
                for (int u = 0; u < 4; ++u) {
                    pw[u] = *(const float4*)(wic + (kn + u) * 32 + j0);
                    pi[u] = irow[kn + u];
                }
            }
            #pragma unroll
            for (int u = 0; u < 4; ++u) {
                acc[0] = fmaf(ci4[u], cw4[u].x, acc[0]);
                acc[1] = fmaf(ci4[u], cw4[u].y, acc[1]);
                acc[2] = fmaf(ci4[u], cw4[u].z, acc[2]);
                acc[3] = fmaf(ci4[u], cw4[u].w, acc[3]);
            }
        }
        #pragma unroll
        for (int j = 0; j < 4; ++j) sic[row * 36 + j0 + j] = acc[j];
    }
    __syncthreads();

    // Phase E: logits. n=t&15, rows t>>4 and (t>>4)+16. Batched loads.
    {
        const int n = t & 15, rowp = t >> 4;
        const float* cer = ce + n * 32;
        float a0 = 0.f, a1 = 0.f;
        #pragma unroll
        for (int k0 = 0; k0 < 32; k0 += 8) {
            float cv[8], s0[8], s1[8];
            #pragma unroll
            for (int u = 0; u < 8; ++u) {
                cv[u] = cer[k0 + u];
                s0[u] = sic[rowp * 36 + k0 + u];
                s1[u] = sic[(rowp + 16) * 36 + k0 + u];
            }
            #pragma unroll
            for (int u = 0; u < 8; ++u) {
                a0 = fmaf(s0[u], cv[u], a0);
                a1 = fmaf(s1[u], cv[u], a1);
            }
        }
        sp[rowp * 20 + n] = a0;
        sp[(rowp + 16) * 20 + n] = a1;
    }
    __syncthreads();

    // Phase F: softmax over 16 clusters, one thread per row (serial).
    if (t < 32) {
        float* pr = sp + t * 20;
        float mx = pr[0];
        for (int n = 1; n < 16; ++n) mx = fmaxf(mx, pr[n]);
        float ss = 0.f;
        for (int n = 0; n < 16; ++n) { float e = __expf(pr[n] - mx); pr[n] = e; ss += e; }
        float inv = 1.f / ss;
        for (int n = 0; n < 16; ++n) pr[n] *= inv;
    }
    __syncthreads();

    // Phase G: cl = p@ce. row=t>>3, 4 cols per thread, pipelined.
    {
        const int row = t >> 3, j0 = (t & 7) * 4;
        const int c = c0 + row;
        const float* prow = sp + row * 20;
        float acc[4] = {0.f, 0.f, 0.f, 0.f};
        float4 pc[4];
        float  pp[4];
        #pragma unroll
        for (int u = 0; u < 4; ++u) {
            pc[u] = *(const float4*)(ce + u * 32 + j0);
            pp[u] = prow[u];
        }
        for (int n0 = 0; n0 < 16; n0 += 4) {
            float4 cc4[4];
            float  cp4[4];
            #pragma unroll
            for (int u = 0; u < 4; ++u) { cc4[u] = pc[u]; cp4[u] = pp[u]; }
            const int nn = n0 + 4;
            if (nn < 16) {
                #pragma unroll
                for (int u = 0; u < 4; ++u) {
                    pc[u] = *(const float4*)(ce + (nn + u) * 32 + j0);
                    pp[u] = prow[nn + u];
                }
            }
            #pragma unroll
            for (int u = 0; u < 4; ++u) {
                acc[0] = fmaf(cp4[u], cc4[u].x, acc[0]);
                acc[1] = fmaf(cp4[u], cc4[u].y, acc[1]);
                acc[2] = fmaf(cp4[u], cc4[u].z, acc[2]);
                acc[3] = fmaf(cp4[u], cc4[u].w, acc[3]);
            }
        }
        #pragma unroll
        for (int j = 0; j < 4; ++j) {
            scl[row * 36 + j0 + j] = acc[j];
            vt[(size_t)(b * 192 + 160 + j0 + j) * 2048 + c] = f2bf(acc[j]);
        }
    }
    __syncthreads();

    // Phase H: ge = [id|cl]@wg + bg -> bf16. Two pipelined 32-loops.
    {
        const int row = t >> 3, j0 = (t & 7) * 4;
        const int r = r0 + row;
        const float* irow = sid + row * 36;
        const float* crow = scl + row * 36;
        float acc[4];
        #pragma unroll
        for (int j = 0; j < 4; ++j) acc[j] = bg[j0 + j];
        // id part
        {
            float4 pw[4];
            float  pi[4];
            #pragma unroll
            for (int u = 0; u < 4; ++u) {
                pw[u] = *(const float4*)(wg + u * 32 + j0);
                pi[u] = irow[u];
            }
            for (int k0 = 0; k0 < 32; k0 += 4) {
                float4 cw4[4];
                float  ci4[4];
                #pragma unroll
                for (int u = 0; u < 4; ++u) { cw4[u] = pw[u]; ci4[u] = pi[u]; }
                const int kn = k0 + 4;
                if (kn < 32) {
                    #pragma unroll
                    for (int u = 0; u < 4; ++u) {
                        pw[u] = *(const float4*)(wg + (kn + u) * 32 + j0);
                        pi[u] = irow[kn + u];
                    }
                }
                #pragma unroll
                for (int u = 0; u < 4; ++u) {
                    acc[0] = fmaf(ci4[u], cw4[u].x, acc[0]);
                    acc[1] = fmaf(ci4[u], cw4[u].y, acc[1]);
                    acc[2] = fmaf(ci4[u], cw4[u].z, acc[2]);
                    acc[3] = fmaf(ci4[u], cw4[u].w, acc[3]);
                }
            }
        }
        // cl part
        {
            float4 pw[4];
            float  pcv[4];
            #pragma unroll
            for (int u = 0; u < 4; ++u) {
                pw[u] = *(const float4*)(wg + (32 + u) * 32 + j0);
                pcv[u] = crow[u];
            }
            for (int k0 = 0; k0 < 32; k0 += 4) {
                float4 cw4[4];
                float  cc4[4];
                #pragma unroll
                for (int u = 0; u < 4; ++u) { cw4[u] = pw[u]; cc4[u] = pcv[u]; }
                const int kn = k0 + 4;
                if (kn < 32) {
                    #pragma unroll
                    for (int u = 0; u < 4; ++u) {
                        pw[u] = *(const float4*)(wg + (32 + kn + u) * 32 + j0);
                        pcv[u] = crow[kn + u];
                    }
                }
                #pragma unroll
                for (int u = 0; u < 4; ++u) {
                    acc[0] = fmaf(cc4[u], cw4[u].x, acc[0]);
                    acc[1] = fmaf(cc4[u], cw4[u].y, acc[1]);
                    acc[2] = fmaf(cc4[u], cw4[u].z, acc[2]);
                    acc[3] = fmaf(cc4[u], cw4[u].w, acc[3]);
                }
            }
        }
        #pragma unroll
        for (int j = 0; j < 4; ++j)
            geb16[(size_t)r * 32 + j0 + j] = f2bf(acc[j]);
    }
}

// ---------------------------------------------------------------------------
// k1b: sumV[b][ch] = sum_m VT[b][ch][m] (fp32 accumulate of bf16).
// ---------------------------------------------------------------------------
__global__ __launch_bounds__(256) void k1b_sumv(
    const unsigned short* __restrict__ vt, float* __restrict__ sumv)
{
    __shared__ float red[256];
    const int ch = blockIdx.x, b = blockIdx.y, t = threadIdx.x;
    const unsigned short* row = vt + (size_t)(b * 192 + ch) * 2048;
    float a = 0.f;
    #pragma unroll
    for (int j = 0; j < 8; ++j) a += bf2f(row[t * 8 + j]);
    red[t] = a; __syncthreads();
    for (int off = 128; off > 0; off >>= 1) {
        if (t < off) red[t] += red[t + off];
        __syncthreads();
    }
    if (t == 0) sumv[b * 192 + ch] = red[0];
}

// ---------------------------------------------------------------------------
// k2: all-MFMA core. Round-7 verified version: 256 thr, sGeO + dbuf
// sGe/sVtA + reg prefetch, 2 barriers/iter, XCD remap, diag hoist.
// ---------------------------------------------------------------------------
__global__ __launch_bounds__(256) void k2_fused(
    const unsigned short* __restrict__ geb16,
    const unsigned short* __restrict__ vt,
    const float* __restrict__ sumv,
    unsigned short* __restrict__ aggb)
{
    __shared__ unsigned short sGeO[64 * 40];
    __shared__ unsigned short sGe[2][64 * 40];
    __shared__ unsigned short sVtA[2][192 * 72];
    __shared__ unsigned short dw[64 * 72];
    __shared__ float s_sum[192];
    __shared__ float sinv[64];
    float* lpbuf = (float*)sVtA;   // [64][68] fp32, used only after main loop

    const int t = threadIdx.x;
    // XCD-bijective remap: 512 blocks = 8 XCDs x 64. XCD x gets contiguous
    // chunk -> 2 batches per XCD -> vt working set 1.5MB < 4MB XCD-L2.
    const int lin = blockIdx.x + gridDim.x * blockIdx.y;   // 0..511
    const int nb = (lin & 7) * 64 + (lin >> 3);
    const int o0 = (nb & 31) * 64;
    const int b = nb >> 5;
    const unsigned short* geb = geb16 + (size_t)b * 2048 * 32;
    const unsigned short* vtb = vt + (size_t)b * 192 * 2048;

    const int lane = t & 63;
    const int mg = t >> 6;
    const int col = lane & 31;
    const int grp = lane >> 5;
    const int os = (mg & 1) * 32;
    const int ms = (mg >> 1) * 32;
    const int orow0 = (mg & 1) * 32;
    const int dbase = (mg >> 1) * 96;

    const int ge_row = t >> 2, ge_c8 = t & 3;

    short8 rGe;
    short8 rVt0, rVt1, rVt2, rVt3, rVt4, rVt5;

    if (t < 192) s_sum[t] = sumv[b * 192 + t];
    {
        short8 v = *(const short8*)(geb + (size_t)(o0 + ge_row) * 32 + ge_c8 * 8);
        *(short8*)(sGeO + ge_row * 40 + ge_c8 * 8) = v;
    }
    {
        rGe = *(const short8*)(geb + (size_t)ge_row * 32 + ge_c8 * 8);
        int i0;
        i0 = t + 0 * 256; rVt0 = *(const short8*)(vtb + (size_t)(i0 >> 3) * 2048 + 0 + (i0 & 7) * 8);
        i0 = t + 1 * 256; rVt1 = *(const short8*)(vtb + (size_t)(i0 >> 3) * 2048 + 0 + (i0 & 7) * 8);
        i0 = t + 2 * 256; rVt2 = *(const short8*)(vtb + (size_t)(i0 >> 3) * 2048 + 0 + (i0 & 7) * 8);
        i0 = t + 3 * 256; rVt3 = *(const short8*)(vtb + (size_t)(i0 >> 3) * 2048 + 0 + (i0 & 7) * 8);
        i0 = t + 4 * 256; rVt4 = *(const short8*)(vtb + (size_t)(i0 >> 3) * 2048 + 0 + (i0 & 7) * 8);
        i0 = t + 5 * 256; rVt5 = *(const short8*)(vtb + (size_t)(i0 >> 3) * 2048 + 0 + (i0 & 7) * 8);
    }
    {
        *(short8*)(sGe[0] + ge_row * 40 + ge_c8 * 8) = rGe;
        int i0;
        i0 = t + 0 * 256; *(short8*)(sVtA[0] + (i0 >> 3) * 72 + (i0 & 7) * 8) = rVt0;
        i0 = t + 1 * 256; *(short8*)(sVtA[0] + (i0 >> 3) * 72 + (i0 & 7) * 8) = rVt1;
        i0 = t + 2 * 256; *(short8*)(sVtA[0] + (i0 >> 3) * 72 + (i0 & 7) * 8) = rVt2;
        i0 = t + 3 * 256; *(short8*)(sVtA[0] + (i0 >> 3) * 72 + (i0 & 7) * 8) = rVt3;
        i0 = t + 4 * 256; *(short8*)(sVtA[0] + (i0 >> 3) * 72 + (i0 & 7) * 8) = rVt4;
        i0 = t + 5 * 256; *(short8*)(sVtA[0] + (i0 >> 3) * 72 + (i0 & 7) * 8) = rVt5;
    }
    __syncthreads();

    f32x16 acc0, acc1, acc2;
    #pragma unroll
    for (int i = 0; i < 16; ++i) { acc0[i] = 0.f; acc1[i] = 0.f; acc2[i] = 0.f; }
    float lpA[16];
    #pragma unroll
    for (int i = 0; i < 16; ++i) lpA[i] = 0.f;

    int cur = 0;
    for (int m0 = 0; m0 < 2048; m0 += 64) {
        const bool have_next = (m0 + 64 < 2048);

        if (have_next) {
            const int mn = m0 + 64;
            rGe = *(const short8*)(geb + (size_t)(mn + ge_row) * 32 + ge_c8 * 8);
            int i0;
            i0 = t + 0 * 256; rVt0 = *(const short8*)(vtb + (size_t)(i0 >> 3) * 2048 + mn + (i0 & 7) * 8);
            i0 = t + 1 * 256; rVt1 = *(const short8*)(vtb + (size_t)(i0 >> 3) * 2048 + mn + (i0 & 7) * 8);
            i0 = t + 2 * 256; rVt2 = *(const short8*)(vtb + (size_t)(i0 >> 3) * 2048 + mn + (i0 & 7) * 8);
            i0 = t + 3 * 256; rVt3 = *(const short8*)(vtb + (size_t)(i0 >> 3) * 2048 + mn + (i0 & 7) * 8);
            i0 = t + 4 * 256; rVt4 = *(const short8*)(vtb + (size_t)(i0 >> 3) * 2048 + mn + (i0 & 7) * 8);
            i0 = t + 5 * 256; rVt5 = *(const short8*)(vtb + (size_t)(i0 >> 3) * 2048 + mn + (i0 & 7) * 8);
        }

        f32x16 sacc;
        #pragma unroll
        for (int i = 0; i < 16; ++i) sacc[i] = 0.f;
        #pragma unroll
        for (int ks = 0; ks < 2; ++ks) {
            short8 A  = *(const short8*)(sGeO + (os + col) * 40 + ks * 16 + grp * 8);
            short8 Bf = *(const short8*)(sGe[cur] + (ms + col) * 40 + ks * 16 + grp * 8);
            sacc = __builtin_amdgcn_mfma_f32_32x32x16_bf16(A, Bf, sacc, 0, 0, 0);
        }
        {
            const int m_local = ms + col;
            if (m0 != o0) {              // no diagonal in this tile
                #pragma unroll
                for (int r = 0; r < 16; ++r) {
                    int o_local = os + (r & 3) + 8 * (r >> 2) + 4 * grp;
                    float s = sacc[r];
                    float d = (s > 0.f) ? (__expf(s) - 1.f) : 0.f;
                    lpA[r] += d;
                    dw[o_local * 72 + m_local] = f2bf(d);
                }
            } else {
                const int gm = m0 + m_local;
                #pragma unroll
                for (int r = 0; r < 16; ++r) {
                    int o_local = os + (r & 3) + 8 * (r >> 2) + 4 * grp;
                    float s = sacc[r];
                    float d = (gm == o0 + o_local) ? -1.f
                            : ((s > 0.f) ? (__expf(s) - 1.f) : 0.f);
                    lpA[r] += d;
                    dw[o_local * 72 + m_local] = f2bf(d);
                }
            }
        }
        __syncthreads();   // dw ready

        #pragma unroll
        for (int ks = 0; ks < 4; ++ks) {
            short8 A  = *(const short8*)(dw + (orow0 + col) * 72 + ks * 16 + grp * 8);
            short8 B0 = *(const short8*)(sVtA[cur] + (dbase + col) * 72 + ks * 16 + grp * 8);
            short8 B1 = *(const short8*)(sVtA[cur] + (dbase + 32 + col) * 72 + ks * 16 + grp * 8);
            short8 B2 = *(const short8*)(sVtA[cur] + (dbase + 64 + col) * 72 + ks * 16 + grp * 8);
            acc0 = __builtin_amdgcn_mfma_f32_32x32x16_bf16(A, B0, acc0, 0, 0, 0);
            acc1 = __builtin_amdgcn_mfma_f32_32x32x16_bf16(A, B1, acc1, 0, 0, 0);
            acc2 = __builtin_amdgcn_mfma_f32_32x32x16_bf16(A, B2, acc2, 0, 0, 0);
        }

        if (have_next) {
            const int nbuf = cur ^ 1;
            *(short8*)(sGe[nbuf] + ge_row * 40 + ge_c8 * 8) = rGe;
            int i0;
            i0 = t + 0 * 256; *(short8*)(sVtA[nbuf] + (i0 >> 3) * 72 + (i0 & 7) * 8) = rVt0;
            i0 = t + 1 * 256; *(short8*)(sVtA[nbuf] + (i0 >> 3) * 72 + (i0 & 7) * 8) = rVt1;
            i0 = t + 2 * 256; *(short8*)(sVtA[nbuf] + (i0 >> 3) * 72 + (i0 & 7) * 8) = rVt2;
            i0 = t + 3 * 256; *(short8*)(sVtA[nbuf] + (i0 >> 3) * 72 + (i0 & 7) * 8) = rVt3;
            i0 = t + 4 * 256; *(short8*)(sVtA[nbuf] + (i0 >> 3) * 72 + (i0 & 7) * 8) = rVt4;
            i0 = t + 5 * 256; *(short8*)(sVtA[nbuf] + (i0 >> 3) * 72 + (i0 & 7) * 8) = rVt5;
        }
        __syncthreads();
        cur ^= 1;
    }

    {
        const int widx = mg >> 1;
        #pragma unroll
        for (int r = 0; r < 16; ++r) {
            int ol = os + (r & 3) + 8 * (r >> 2) + 4 * grp;
            lpbuf[(widx * 32 + col) * 68 + ol] = lpA[r];
        }
    }
    __syncthreads();
    if (t < 64) {
        float l = 2048.f;
        for (int i = 0; i < 64; ++i) l += lpbuf[i * 68 + t];
        sinv[t] = 1.f / l;
    }
    __syncthreads();

    {
        f32x16 av[3] = {acc0, acc1, acc2};
        unsigned short* ab = aggb + (size_t)b * 2048 * 192;
        #pragma unroll
        for (int n = 0; n < 3; ++n) {
            int chn = dbase + n * 32 + col;
            float sv = s_sum[chn];
            #pragma unroll
            for (int r = 0; r < 16; ++r) {
                int ol = orow0 + (r & 3) + 8 * (r >> 2) + 4 * grp;
                ab[(size_t)(o0 + ol) * 192 + chn] =
                    f2bf((sv + av[n][r]) * sinv[ol]);
            }
        }
    }
}

// ---------------------------------------------------------------------------
// k3a_split: cw (fp32 [2048][192]) -> cwhi + cwlo (bf16 each).
// ---------------------------------------------------------------------------
__global__ __launch_bounds__(256) void k3a_split(
    const float* __restrict__ cw, unsigned short* __restrict__ cwhi,
    unsigned short* __restrict__ cwlo)
{
    const int idx = blockIdx.x * 256 + threadIdx.x;   // grid 1536 -> 393216
    float v = cw[idx];
    unsigned short h = f2bf(v);
    cwhi[idx] = h;
    cwlo[idx] = f2bf(v - bf2f(h));
}

// ---------------------------------------------------------------------------
// k3_mfma_sk: wpart[slot][d][l] = sum_{o in ks-range} agg[o][d]*cw[o][l]
// via bf16 MFMA with cw hi/lo split. No LDS, no barriers.
// ---------------------------------------------------------------------------
__global__ __launch_bounds__(256) void k3_mfma_sk(
    const unsigned short* __restrict__ aggb,
    const unsigned short* __restrict__ cwhi,
    const unsigned short* __restrict__ cwlo,
    float* __restrict__ wpart)
{
    const int t = threadIdx.x;
    const int slot = blockIdx.z;
    const int b = slot >> 3;
    const int ks = slot & 7;
    const int d0 = blockIdx.x * 64;
    const int l0 = blockIdx.y * 64;
    const unsigned short* ab = aggb + (size_t)b * 2048 * 192;

    const int lane = t & 63;
    const int w = t >> 6;
    const int col = lane & 31;
    const int grp = lane >> 5;
    const int drow = d0 + (w & 1) * 32 + col;    // A row for this lane
    const int lrow = l0 + (w >> 1) * 32 + col;   // B row for this lane

    f32x16 acc;
    #pragma unroll
    for (int i = 0; i < 16; ++i) acc[i] = 0.f;

    const int obase = ks * 256;
    #pragma unroll 4
    for (int ostep = 0; ostep < 16; ++ostep) {
        const int ob = obase + ostep * 16 + grp * 8;
        short8 A, Bh, Bl;
        #pragma unroll
        for (int i = 0; i < 8; ++i) {
            const size_t ro = (size_t)(ob + i) * 192;
            A[i]  = (short)ab[ro + drow];
            Bh[i] = (short)cwhi[ro + lrow];
            Bl[i] = (short)cwlo[ro + lrow];
        }
        acc = __builtin_amdgcn_mfma_f32_32x32x16_bf16(A, Bh, acc, 0, 0, 0);
        acc = __builtin_amdgcn_mfma_f32_32x32x16_bf16(A, Bl, acc, 0, 0, 0);
    }

    float* wp = wpart + (size_t)slot * 36864;
    const int lcol = l0 + (w >> 1) * 32 + col;
    #pragma unroll
    for (int r = 0; r < 16; ++r) {
        int dl = d0 + (w & 1) * 32 + (r & 3) + 8 * (r >> 2) + 4 * grp;
        wp[(size_t)dl * 192 + lcol] = acc[r];
    }
}

// ---------------------------------------------------------------------------
// k3_ctx_sk: split-K partial of w-sum (fp32 fallback). blockIdx.z = b*8+ks.
// ---------------------------------------------------------------------------
__global__ __launch_bounds__(256) void k3_ctx_sk(
    const unsigned short* __restrict__ aggb, const float* __restrict__ cw,
    float* __restrict__ wpart)
{
    __shared__ float sA[64 * 68];
    __shared__ float sW[64 * 68];
    const int t = threadIdx.x;
    const int slot = blockIdx.z;
    const int b = slot >> 3;
    const int ks = slot & 7;
    const int d0 = blockIdx.x * 64;
    const int l0 = blockIdx.y * 64;
    const unsigned short* ab = aggb + (size_t)b * 2048 * 192;
    const int ti = t >> 4, tj = t & 15;
    float acc[4][4] = {{0.f}};

    for (int o0 = ks * 256; o0 < ks * 256 + 256; o0 += 64) {
        for (int i = t; i < 4096; i += 256) {
            int oo = i >> 6, dd = i & 63;
            sA[oo * 68 + dd] = bf2f(ab[(size_t)(o0 + oo) * 192 + d0 + dd]);
            sW[oo * 68 + dd] = cw[(size_t)(o0 + oo) * 192 + l0 + dd];
        }
        __syncthreads();
        for (int o = 0; o < 64; ++o) {
            const float* ap = sA + o * 68 + ti * 4;
            const float* wp = sW + o * 68 + tj * 4;
            float a0 = ap[0], a1 = ap[1], a2 = ap[2], a3 = ap[3];
            float w0 = wp[0], w1v = wp[1], w2v = wp[2], w3 = wp[3];
            acc[0][0] = fmaf(a0, w0, acc[0][0]); acc[0][1] = fmaf(a0, w1v, acc[0][1]);
            acc[0][2] = fmaf(a0, w2v, acc[0][2]); acc[0][3] = fmaf(a0, w3, acc[0][3]);
            acc[1][0] = fmaf(a1, w0, acc[1][0]); acc[1][1] = fmaf(a1, w1v, acc[1][1]);
            acc[1][2] = fmaf(a1, w2v, acc[1][2]); acc[1][3] = fmaf(a1, w3, acc[1][3]);
            acc[2][0] = fmaf(a2, w0, acc[2][0]); acc[2][1] = fmaf(a2, w1v, acc[2][1]);
            acc[2][2] = fmaf(a2, w2v, acc[2][2]); acc[2][3] = fmaf(a2, w3, acc[2][3]);
            acc[3][0] = fmaf(a3, w0, acc[3][0]); acc[3][1] = fmaf(a3, w1v, acc[3][1]);
            acc[3][2] = fmaf(a3, w2v, acc[3][2]); acc[3][3] = fmaf(a3, w3, acc[3][3]);
        }
        __syncthreads();
    }
    float* wp = wpart + (size_t)slot * 36864;
    #pragma unroll
    for (int i = 0; i < 4; ++i)
        #pragma unroll
        for (int j = 0; j < 4; ++j)
            wp[(d0 + ti * 4 + i) * 192 + l0 + tj * 4 + j] = acc[i][j];
}

// ---------------------------------------------------------------------------
__global__ __launch_bounds__(256) void k3r_reduce(
    const float* __restrict__ wpart, float* __restrict__ wraw)
{
    const int idx = blockIdx.x * 256 + threadIdx.x;
    const int b = blockIdx.y;
    const float* base = wpart + (size_t)b * 8 * 36864 + idx;
    float a = 0.f;
    #pragma unroll
    for (int ks = 0; ks < 8; ++ks) a += base[(size_t)ks * 36864];
    wraw[(size_t)b * 36864 + idx] = tanhf(a);
}

// ---------------------------------------------------------------------------
// k3_ctx: single-pass fallback (used only if ws too small for wpart).
// ---------------------------------------------------------------------------
__global__ __launch_bounds__(256) void k3_ctx(
    const unsigned short* __restrict__ aggb, const float* __restrict__ cw,
    float* __restrict__ wraw)
{
    __shared__ float sA[64 * 68];
    __shared__ float sW[64 * 68];
    const int t = threadIdx.x;
    const int b = blockIdx.z;
    const int d0 = blockIdx.x * 64;
    const int l0 = blockIdx.y * 64;
    const unsigned short* ab = aggb + (size_t)b * 2048 * 192;
    const int ti = t >> 4, tj = t & 15;
    float acc[4][4] = {{0.f}};

    for (int o0 = 0; o0 < 2048; o0 += 64) {
        for (int i = t; i < 4096; i += 256) {
            int oo = i >> 6, dd = i & 63;
            sA[oo * 68 + dd] = bf2f(ab[(size_t)(o0 + oo) * 192 + d0 + dd]);
            sW[oo * 68 + dd] = cw[(size_t)(o0 + oo) * 192 + l0 + dd];
        }
        __syncthreads();
        for (int o = 0; o < 64; ++o) {
            const float* ap = sA + o * 68 + ti * 4;
            const float* wp = sW + o * 68 + tj * 4;
            float a0 = ap[0], a1 = ap[1], a2 = ap[2], a3 = ap[3];
            float w0 = wp[0], w1v = wp[1], w2v = wp[2], w3 = wp[3];
            acc[0][0] = fmaf(a0, w0, acc[0][0]); acc[0][1] = fmaf(a0, w1v, acc[0][1]);
            acc[0][2] = fmaf(a0, w2v, acc[0][2]); acc[0][3] = fmaf(a0, w3, acc[0][3]);
            acc[1][0] = fmaf(a1, w0, acc[1][0]); acc[1][1] = fmaf(a1, w1v, acc[1][1]);
            acc[1][2] = fmaf(a1, w2v, acc[1][2]); acc[1][3] = fmaf(a1, w3, acc[1][3]);
            acc[2][0] = fmaf(a2, w0, acc[2][0]); acc[2][1] = fmaf(a2, w1v, acc[2][1]);
            acc[2][2] = fmaf(a2, w2v, acc[2][2]); acc[2][3] = fmaf(a2, w3, acc[2][3]);
            acc[3][0] = fmaf(a3, w0, acc[3][0]); acc[3][1] = fmaf(a3, w1v, acc[3][1]);
            acc[3][2] = fmaf(a3, w2v, acc[3][2]); acc[3][3] = fmaf(a3, w3, acc[3][3]);
        }
        __syncthreads();
    }
    float* wb = wraw + (size_t)b * 36864;
    #pragma unroll
    for (int i = 0; i < 4; ++i)
        #pragma unroll
        for (int j = 0; j < 4; ++j)
            wb[(d0 + ti * 4 + i) * 192 + l0 + tj * 4 + j] = tanhf(acc[i][j]);
}

// ---------------------------------------------------------------------------
// k3b_m2: 2-deep register pipeline (8 loads in flight).
// ---------------------------------------------------------------------------
__global__ __launch_bounds__(192) void k3b_m2(
    const float* __restrict__ wmat, const float* __restrict__ wl,
    float* __restrict__ m2)
{
    const int t = threadIdx.x;
    const int b = blockIdx.y;
    const int d = blockIdx.x * 2 + (t / 96);
    const int l = t % 96;
    const float* wrow = wmat + (size_t)b * 36864 + d * 192;
    float acc = wl[d * 96 + l];
    float pa[8], pb[8];
    #pragma unroll
    for (int u = 0; u < 8; ++u) { pa[u] = wrow[u]; pb[u] = wl[u * 96 + l]; }
    for (int k0 = 0; k0 < 192; k0 += 8) {
        float ca[8], cb[8];
        #pragma unroll
        for (int u = 0; u < 8; ++u) { ca[u] = pa[u]; cb[u] = pb[u]; }
        const int kn = k0 + 8;
        if (kn < 192) {
            #pragma unroll
            for (int u = 0; u < 8; ++u) {
                pa[u] = wrow[kn + u];
                pb[u] = wl[(kn + u) * 96 + l];
            }
        }
        #pragma unroll
        for (int u = 0; u < 8; ++u) acc = fmaf(ca[u], cb[u], acc);
    }
    m2[(size_t)b * 18432 + d * 96 + l] = acc;
}

// ---------------------------------------------------------------------------
// k4_tiled: out = gcn@M2 + bl. 64 rows x 96 cols per block (grid 32x16,
// 192 thr). m2 staged once in LDS (73.7 KB -> 2 blocks/CU). Round-26:
// reverted to this round-8-verified staged version (global-m2 was -34us).
// ---------------------------------------------------------------------------
__global__ __launch_bounds__(192) void k4_tiled(
    const float* __restrict__ x, const unsigned short* __restrict__ vt,
    const float* __restrict__ m2, const float* __restrict__ bl,
    float* __restrict__ out)
{
    __shared__ float sm2[192 * 96];
    const int t = threadIdx.x;           // 0..191
    const int rblk = blockIdx.x;         // 0..31
    const int b = blockIdx.y;
    // stage m2 (4608 float4, 24 per thread)
    {
        const float4* src = (const float4*)(m2 + (size_t)b * 18432);
        float4* dst = (float4*)sm2;
        #pragma unroll
        for (int i = 0; i < 24; ++i) dst[t + i * 192] = src[t + i * 192];
    }
    __syncthreads();

    const int rg = t / 12;               // 0..15
    const int cg = t % 12;               // 0..11
    const int j0 = cg * 8;
    const int cloc = rblk * 64 + rg * 4; // within-batch row
    const int rr = b * 2048 + cloc;      // global row
    float acc[4][8];
    #pragma unroll
    for (int i = 0; i < 4; ++i)
        #pragma unroll
        for (int j = 0; j < 8; ++j) acc[i][j] = bl[j0 + j];

    for (int k0 = 0; k0 < 128; k0 += 8) {
        float rv[4][8];
        #pragma unroll
        for (int i = 0; i < 4; ++i) {
            const float4* xr = (const float4*)(x + (size_t)(rr + i) * 128 + k0);
            float4 a = xr[0], c4 = xr[1];
            rv[i][0] = a.x; rv[i][1] = a.y; rv[i][2] = a.z; rv[i][3] = a.w;
            rv[i][4] = c4.x; rv[i][5] = c4.y; rv[i][6] = c4.z; rv[i][7] = c4.w;
        }
        #pragma unroll
        for (int kk = 0; kk < 8; ++kk) {
            const float* mr = sm2 + (k0 + kk) * 96 + j0;
            float mv[8];
            #pragma unroll
            for (int j = 0; j < 8; ++j) mv[j] = mr[j];
            #pragma unroll
            for (int i = 0; i < 4; ++i)
                #pragma unroll
                for (int j = 0; j < 8; ++j)
                    acc[i][j] = fmaf(rv[i][kk], mv[j], acc[i][j]);
        }
    }
    for (int k = 128; k < 192; ++k) {
        const unsigned short* vr = vt + (size_t)(b * 192 + k) * 2048 + cloc;
        float rv0 = bf2f(vr[0]), rv1 = bf2f(vr[1]);
        float rv2 = bf2f(vr[2]), rv3 = bf2f(vr[3]);
        const float* mr = sm2 + k * 96 + j0;
        #pragma unroll
        for (int j = 0; j < 8; ++j) {
            float mv = mr[j];
            acc[0][j] = fmaf(rv0, mv, acc[0][j]);
            acc[1][j] = fmaf(rv1, mv, acc[1][j]);
            acc[2][j] = fmaf(rv2, mv, acc[2][j]);
            acc[3][j] = fmaf(rv3, mv, acc[3][j]);
        }
    }
    #pragma unroll
    for (int i = 0; i < 4; ++i) {
        float* orow = out + (size_t)(rr + i) * 96 + j0;
        *(float4*)orow = make_float4(acc[i][0], acc[i][1], acc[i][2], acc[i][3]);
        *(float4*)(orow + 4) = make_float4(acc[i][4], acc[i][5], acc[i][6], acc[i][7]);
    }
}

// ---------------------------------------------------------------------------
extern "C" void kernel_launch(void* const* d_in, const int* in_sizes, int n_in,
                              void* d_out, int out_size, void* d_ws, size_t ws_size,
                              hipStream_t stream) {
    const float* x      = (const float*)d_in[0];
    const float* id_emb = (const float*)d_in[1];
    const float* w1     = (const float*)d_in[2];
    const float* b1     = (const float*)d_in[3];
    const float* w2     = (const float*)d_in[4];
    const float* b2     = (const float*)d_in[5];
    const float* ce     = (const float*)d_in[6];
    const float* wic    = (const float*)d_in[7];
    const float* bic    = (const float*)d_in[8];
    const float* wg     = (const float*)d_in[9];
    const float* bg     = (const float*)d_in[10];
    const float* cw     = (const float*)d_in[11];
    const float* wl     = (const float*)d_in[12];
    const float* bl     = (const float*)d_in[13];
    float* out = (float*)d_out;

    float* ws = (float*)d_ws;
    unsigned short* vt    = (unsigned short*)ws;             // 3,145,728 f-eq
    unsigned short* geb16 = (unsigned short*)(ws + 3145728); //   524,288 f-eq
    unsigned short* aggb  = (unsigned short*)(ws + 3670016); // 3,145,728 f-eq
    float* wraw  = ws + 6815744;                             //   589,824
    float* m2    = ws + 7405568;                             //   294,912
    float* sumv  = ws + 7700480;                             //     3,072
    float* wpart = ws + 7703552;                             // 4,718,592 (opt)
    unsigned short* cwhi = (unsigned short*)(ws + 12422144); //   196,608 f-eq
    unsigned short* cwlo = cwhi + 393216;                    //   196,608 f-eq
    const size_t need_sk   = (7703552ull + 4718592ull) * 4ull;            // 49.7 MB
    const size_t need_mfma = (7703552ull + 4718592ull + 393216ull) * 4ull; // 51.3 MB
    const bool use_mfma = (ws_size >= need_mfma);
    const bool use_sk   = (ws_size >= need_sk);

    hipLaunchKernelGGL(k0_transpose_x, dim3(32, 16), dim3(256), 0, stream, x, vt);
    hipLaunchKernelGGL(k1_tiled, dim3(1024), dim3(256), 0, stream,
                       x, id_emb, w1, b1, w2, b2, ce, wic, bic, wg, bg, vt, geb16);
    hipLaunchKernelGGL(k1b_sumv, dim3(192, 16), dim3(256), 0, stream, vt, sumv);
    hipLaunchKernelGGL(k2_fused, dim3(32, 16), dim3(256), 0, stream,
                       geb16, vt, sumv, aggb);
    if (use_mfma) {
        hipLaunchKernelGGL(k3a_split, dim3(1536), dim3(256), 0, stream,
                           cw, cwhi, cwlo);
        hipLaunchKernelGGL(k3_mfma_sk, dim3(3, 3, 128), dim3(256), 0, stream,
                           aggb, cwhi, cwlo, wpart);
        hipLaunchKernelGGL(k3r_reduce, dim3(144, 16), dim3(256), 0, stream,
                           wpart, wraw);
    } else if (use_sk) {
        hipLaunchKernelGGL(k3_ctx_sk, dim3(3, 3, 128), dim3(256), 0, stream,
                           aggb, cw, wpart);
        hipLaunchKernelGGL(k3r_reduce, dim3(144, 16), dim3(256), 0, stream,
                           wpart, wraw);
    } else {
        hipLaunchKernelGGL(k3_ctx, dim3(3, 3, 16), dim3(256), 0, stream,
                           aggb, cw, wraw);
    }
    hipLaunchKernelGGL(k3b_m2, dim3(96, 16), dim3(192), 0, stream,
                       wraw, wl, m2);
    hipLaunchKernelGGL(k4_tiled, dim3(32, 16), dim3(192), 0, stream,
                       x, vt, m2, bl, out);
}